// Round 3
// baseline (456.209 us; speedup 1.0000x reference)
//
#include <hip/hip_runtime.h>
#include <math.h>

#define B_  2
#define L_  2048
#define HID_ 2048
#define H_  16
#define D_  128
#define FAN_IN 0.02209708691207961f   // 1/sqrt(2048)
#define SM_SCALE 0.08838834764831845f // 1/sqrt(128)
#define LOG2E 1.4426950408889634

typedef _Float16 f16;
typedef unsigned int u32;
typedef __attribute__((ext_vector_type(4))) _Float16 f16x4;
typedef __attribute__((ext_vector_type(8))) _Float16 f16x8;
typedef __attribute__((ext_vector_type(4))) float f32x4;

// soft-cap poly in log2 domain: f(x) = 30*tanh(x*SM_SCALE/30)*LOG2E
#define CAP_C0 0.12751738960681625f
#define CAP_C1 (-3.690028637e-7f)
#define CAP_C2 (1.28121e-12f)
#define FIXED_M2 8.0f    // fixed softmax max in log2 units

__device__ __forceinline__ float fexp2(float x) {
#if __has_builtin(__builtin_amdgcn_exp2f)
    return __builtin_amdgcn_exp2f(x);
#else
    return exp2f(x);
#endif
}
__device__ __forceinline__ float frcp(float x) {
#if __has_builtin(__builtin_amdgcn_rcpf)
    return __builtin_amdgcn_rcpf(x);
#else
    return 1.0f / x;
#endif
}
__device__ __forceinline__ void gload_lds16(const void* g, void* l) {
#if __has_builtin(__builtin_amdgcn_global_load_lds)
    __builtin_amdgcn_global_load_lds(
        (const __attribute__((address_space(1))) u32*)g,
        (__attribute__((address_space(3))) u32*)l, 16, 0, 0);
#else
    *(uint4*)l = *(const uint4*)g;
#endif
}

// ---------------------------------------------------------------------------
// fp32 -> f16 conversion for hs + 4 weight matrices.  grid (4096, 5)
// ---------------------------------------------------------------------------
__global__ __launch_bounds__(256) void cvt5(
    const float* __restrict__ s0, const float* __restrict__ s1,
    const float* __restrict__ s2, const float* __restrict__ s3,
    const float* __restrict__ s4,
    f16* __restrict__ d0, f16* __restrict__ d1, f16* __restrict__ d2,
    f16* __restrict__ d3, f16* __restrict__ d4, int n0, int nw)
{
    const int seg = blockIdx.y;
    const float* s = seg==0?s0:seg==1?s1:seg==2?s2:seg==3?s3:s4;
    f16* d = seg==0?d0:seg==1?d1:seg==2?d2:seg==3?d3:d4;
    const int n = (seg==0) ? n0 : nw;
    const int i = (blockIdx.x*256 + threadIdx.x)*8;
    if (i >= n) return;
    float4 a = *(const float4*)&s[i];
    float4 b = *(const float4*)&s[i+4];
    f16x8 o;
    o[0]=(f16)a.x; o[1]=(f16)a.y; o[2]=(f16)a.z; o[3]=(f16)a.w;
    o[4]=(f16)b.x; o[5]=(f16)b.y; o[6]=(f16)b.z; o[7]=(f16)b.w;
    *(f16x8*)&d[i] = o;
}

// ---------------------------------------------------------------------------
// Fused QKV GEMM, 256x256 tile / BK=64 / 8 waves, 8-phase with REGISTER
// double-buffered fragment pipeline (fix for R2's MFMA<->LDS serialization:
// iter time measured 9450 cyc == 4966 MFMA + 4608 LDS serialized).
//
// Window p:  [barrier]  ds_reads(p+1) -> regset[!s] ; stage S(p) ;
//            sched_barrier ; MFMA(p) from regset[s] ; [WV(8) if p odd]
// The reads for p+1 drain on the LDS pipe WHILE the MFMA cluster of p runs
// (compiler emits counted lgkmcnt for the p-operands, leaving p+1 reads in
// flight).  One barrier per phase (8/iter vs R2's 16).
//
// Hazard walk (steady state, regions b0={A0,B0,A1,B1}@0..24576, b1=+32768;
// stage slots P1:b1.A1  P2:b0.B0' P3:b0.A0' P4:b0.B1' P5:b0.A1' P6:b1.B0'
// P7:b1.A0' P8:b1.B1'):
//  - RAW (DMA->ds_read): reads in window p touch regions staged >=5 stage-
//    slots earlier; WV(8) at ends of P1/P3/P5/P7 leaves the 8 newest loads
//    (4 regions) in flight and drains everything older, which is exactly
//    the region consumed 2 windows later.  Verified for all 8 regions.
//  - WAR (ds_read->DMA overwrite): a region's last ds_read completes before
//    the MFMA that consumes it (lgkmcnt), which is before that phase's
//    closing barrier; every stage of that region sits >=1 barrier later.
//  - reg WAR: af/bfr sets alternate per phase (p uses set p&1, loads !(p&1));
//    B consumed over 2 phases (H0,H1) -> bfr loaded every other phase, sets
//    alternate naturally.
// Conflict-free LDS via source-chunk XOR swizzle (0 conflicts, verified).
// T1 XCD-chunked tile swizzle kept (FETCH 143->94 GB verified).
// z==2 writes V transposed (Vt[bh][d][l]) with fp32 v_bias fused.
// ---------------------------------------------------------------------------
__global__ __launch_bounds__(512, 2) void gemm8p_qkv(
    const f16* __restrict__ A,
    const f16* __restrict__ Bq, const f16* __restrict__ Bk,
    const f16* __restrict__ Bv,
    f16* __restrict__ C0, f16* __restrict__ C1,
    f16* __restrict__ Vt, const float* __restrict__ vb,
    int M, int N, int K, float scale)
{
    __shared__ f16 lds[65536];   // 128 KiB

    // ---- T1: XCD-chunked tile swizzle.  lid 0..383; XCD k gets 48
    // consecutive tile indices (same z, contiguous m-panels).
    const u32 lid = blockIdx.x + (blockIdx.y << 3) + (blockIdx.z << 7);
    const u32 swz = (lid & 7) * 48 + (lid >> 3);
    const int n0 = (swz & 7) * 256;
    const int m0 = ((swz >> 3) & 15) * 256;
    const int z  = swz >> 7;
    const f16* Bw = z==0 ? Bq : z==1 ? Bk : Bv;

    const int t = threadIdx.x;            // 0..511
    const int w = t >> 6, l = t & 63;
    const int lane15 = l & 15, quad = l >> 4;
    const int wmr = (w >> 2) * 128;       // wave row block (0/128)
    const int wnc = (w & 3) * 64;         // wave col block
    const int xslot = (quad ^ ((lane15 >> 1) & 3)) * 8;   // swizzled frag slot

    // staging: thread covers rows srow and 128+srow, chunk sc; source chunk
    // pre-swizzled sc ^ ((row>>1)&3) so lane-linear LDS dest is read
    // conflict-free with the same XOR.
    const int srow = t >> 2;
    const int sc   = t & 3;
    const int cs0 = (sc ^ ((srow >> 1) & 3)) * 8;
    const f16* Ag0 = A  + (size_t)(m0 + srow) * K + cs0;
    const f16* Ag1 = A  + (size_t)(m0 + 128 + srow) * K + cs0;
    const f16* Bg0 = Bw + (size_t)(n0 + srow) * K + cs0;
    const f16* Bg1 = Bw + (size_t)(n0 + 128 + srow) * K + cs0;
    f16* const ldst = lds + t * 8;

#define STG_A(BUF, S, KOFF) {                                             \
    gload_lds16(Ag0 + (KOFF), ldst + (BUF) + (S)*16384);                  \
    gload_lds16(Ag1 + (KOFF), ldst + (BUF) + (S)*16384 + 4096); }
#define STG_B(BUF, S, KOFF) {                                             \
    gload_lds16(Bg0 + (KOFF), ldst + (BUF) + (S)*16384 + 8192);           \
    gload_lds16(Bg1 + (KOFF), ldst + (BUF) + (S)*16384 + 12288); }
#define WV(N) asm volatile("s_waitcnt vmcnt(" #N ")" ::: "memory")
#define BAR() __builtin_amdgcn_s_barrier()
#define SBAR() __builtin_amdgcn_sched_barrier(0)

    f32x4 acc[8][4] = {};
    f16x8 af[2][4];
    f16x8 bfr[2][4];

    // read A-fragments for half H of sub-tile (BUFO,S) into set SET
#define RD_A(SET, BUFO, S, H) {                                           \
    _Pragma("unroll")                                                     \
    for (int i = 0; i < 4; i++) {                                         \
        const int r = wmr + (H)*64 + i*16 + lane15;                       \
        af[SET][i] = *(const f16x8*)&lds[(BUFO) + (S)*16384 + r*32 + xslot]; \
    } }
#define RD_B(SET, BUFO, S) {                                              \
    _Pragma("unroll")                                                     \
    for (int j = 0; j < 4; j++) {                                         \
        const int r = wnc + j*16 + lane15;                                \
        bfr[SET][j] = *(const f16x8*)&lds[(BUFO) + (S)*16384 + 8192 + r*32 + xslot]; \
    } }
#define MM(H, AS, BS) {                                                   \
    __builtin_amdgcn_s_setprio(1);                                        \
    _Pragma("unroll")                                                     \
    for (int i = 0; i < 4; i++)                                           \
        _Pragma("unroll")                                                 \
        for (int j = 0; j < 4; j++)                                       \
            acc[(H)*4+i][j] = __builtin_amdgcn_mfma_f32_16x16x32_f16(     \
                af[AS][i], bfr[BS][j], acc[(H)*4+i][j], 0, 0, 0);         \
    __builtin_amdgcn_s_setprio(0); }

    // ---- prologue: stage b0 (tile 0) + b1.B0/A0/B1 (tile 1); drain first
    // two regions; load regset 0 for P1.
    STG_B(0, 0, 0);  STG_A(0, 0, 0);  STG_B(0, 1, 32);  STG_A(0, 1, 32);
    STG_B(32768, 0, 64);  STG_A(32768, 0, 64);  STG_B(32768, 1, 96);
    WV(10); BAR();
    RD_A(0, 0, 0, 0); RD_B(0, 0, 0);

    // ---- steady loop: iters 0..14 cover K-tiles 0..29 (K=2048, 32 tiles)
    const int NIT = (K >> 7) - 1;   // 15
    for (int it = 0; it < NIT; ++it) {
        const int k1A = it * 128 + 96;    // tile 2it+1, ksub1 (A)
        const int kE  = it * 128 + 128;   // tile 2it+2
        const int kO  = it * 128 + 192;   // tile 2it+3

        // P1: mfma(b0,k0,H0); load (b0,k0,H1); stage b1.A1
        RD_A(1, 0, 0, 1);            STG_A(32768, 1, k1A);  SBAR();
        MM(0, 0, 0);  WV(8); BAR();
        // P2: mfma(b0,k0,H1); load (b0,k1,H0)+(b0,k1,B); stage b0.B0'
        RD_A(0, 0, 1, 0); RD_B(1, 0, 1);  STG_B(0, 0, kE);  SBAR();
        MM(1, 1, 0);  BAR();
        // P3: mfma(b0,k1,H0); load (b0,k1,H1); stage b0.A0'
        RD_A(1, 0, 1, 1);            STG_A(0, 0, kE);       SBAR();
        MM(0, 0, 1);  WV(8); BAR();
        // P4: mfma(b0,k1,H1); load (b1,k0,H0)+(b1,k0,B); stage b0.B1'
        RD_A(0, 32768, 0, 0); RD_B(0, 32768, 0);  STG_B(0, 1, kE + 32);  SBAR();
        MM(1, 1, 1);  BAR();
        // P5: mfma(b1,k0,H0); load (b1,k0,H1); stage b0.A1'
        RD_A(1, 32768, 0, 1);        STG_A(0, 1, kE + 32);  SBAR();
        MM(0, 0, 0);  WV(8); BAR();
        // P6: mfma(b1,k0,H1); load (b1,k1,H0)+(b1,k1,B); stage b1.B0''
        RD_A(0, 32768, 1, 0); RD_B(1, 32768, 1);  STG_B(32768, 0, kO);  SBAR();
        MM(1, 1, 0);  BAR();
        // P7: mfma(b1,k1,H0); load (b1,k1,H1); stage b1.A0''
        RD_A(1, 32768, 1, 1);        STG_A(32768, 0, kO);   SBAR();
        MM(0, 0, 1);  WV(8); BAR();
        // P8: mfma(b1,k1,H1); load (b0',k0,H0)+(b0',k0,B); stage b1.B1''
        RD_A(0, 0, 0, 0); RD_B(0, 0, 0);  STG_B(32768, 1, kO + 32);  SBAR();
        MM(1, 1, 1);  BAR();
    }

    // ---- peeled last iter (K-tiles 30,31): only P1 stages (b1.A1 tile 31);
    // waits shrink 8/4/0 as the DMA queue drains.
    {
        const int k1A = NIT * 128 + 96;   // 2016
        RD_A(1, 0, 0, 1);  STG_A(32768, 1, k1A);  SBAR();
        MM(0, 0, 0);  WV(8); BAR();
        RD_A(0, 0, 1, 0); RD_B(1, 0, 1);  SBAR();
        MM(1, 1, 0);  BAR();
        RD_A(1, 0, 1, 1);  SBAR();
        MM(0, 0, 1);  WV(4); BAR();
        RD_A(0, 32768, 0, 0); RD_B(0, 32768, 0);  SBAR();
        MM(1, 1, 1);  BAR();
        RD_A(1, 32768, 0, 1);  SBAR();
        MM(0, 0, 0);  WV(0); BAR();
        RD_A(0, 32768, 1, 0); RD_B(1, 32768, 1);  SBAR();
        MM(1, 1, 0);  BAR();
        RD_A(1, 32768, 1, 1);  SBAR();
        MM(0, 0, 1);  BAR();
        MM(1, 1, 1);
    }

#undef MM
#undef RD_A
#undef RD_B
#undef STG_A
#undef STG_B
#undef WV
#undef BAR
#undef SBAR

    if (z == 2) {
        // V: write transposed with bias.  out(row=b*L+l, col=h*128+d)
        // -> Vt[(b*16+h)*128 + d][l], f16x4 along l.
#pragma unroll
        for (int fi = 0; fi < 8; fi++)
#pragma unroll
            for (int j = 0; j < 4; j++) {
                const int col = n0 + wnc + j*16 + lane15;
                const int row0 = m0 + wmr + fi*16 + quad*4;
                const int b = row0 >> 11, ll = row0 & 2047;
                const int bh = (b << 4) + (col >> 7);
                const float bias = vb[col];
                f16x4 ph;
#pragma unroll
                for (int r = 0; r < 4; r++)
                    ph[r] = (f16)(acc[fi][j][r] * scale + bias);
                *(f16x4*)&Vt[((size_t)(bh*128 + (col & 127)))*(size_t)L_ + ll] = ph;
            }
    } else {
        f16* Cout = z==0 ? C0 : C1;
#pragma unroll
        for (int fi = 0; fi < 8; fi++)
#pragma unroll
            for (int j = 0; j < 4; j++) {
                const int col = n0 + wnc + j*16 + lane15;
#pragma unroll
                for (int r = 0; r < 4; r++) {
                    const int row = m0 + wmr + fi*16 + quad*4 + r;
                    Cout[(size_t)row*N + col] = (f16)(acc[fi][j][r] * scale);
                }
            }
    }
}

// ---------------------------------------------------------------------------
// GEMM C[M,N] = scale * A[M,K] @ Bw[N,K]^T, f16 in, f32 out (final proj).
// 128² two-phase structure (unchanged this round).
// ---------------------------------------------------------------------------
__global__ __launch_bounds__(256) void gemm16_f32out(
    const f16* __restrict__ A, const f16* __restrict__ Bw,
    float* __restrict__ Cout, int M, int N, int K, float scale)
{
    __shared__ f16 As[128*32];
    __shared__ f16 Bs[128*32];
    const int t = threadIdx.x;
    const int w = t >> 6, l = t & 63;
    const int lane15 = l & 15, quad = l >> 4;
    const int m0 = blockIdx.y*128, n0 = blockIdx.x*128;
    const int wm = (w & 1)*64, wn = (w >> 1)*64;

    const int srow = t >> 2;
    const int scol = (((t & 3) ^ ((t >> 3) & 3))) * 8;
    const f16* Ag = A  + (size_t)(m0 + srow)*K + scol;
    const f16* Bg = Bw + (size_t)(n0 + srow)*K + scol;
    f16* Al = As + t*8;
    f16* Bl = Bs + t*8;

    f32x4 acc[4][4] = {};
    for (int k0 = 0; k0 < K; k0 += 32) {
        gload_lds16(Ag + k0,                 Al);
        gload_lds16(Ag + (size_t)64*K + k0,  Al + 2048);
        gload_lds16(Bg + k0,                 Bl);
        gload_lds16(Bg + (size_t)64*K + k0,  Bl + 2048);
        __syncthreads();
        f16x8 af[4], bf[4];
#pragma unroll
        for (int i = 0; i < 4; i++) {
            const int ra = wm + i*16 + lane15;
            const int rb = wn + i*16 + lane15;
            af[i] = *(const f16x8*)&As[ra*32 + ((quad ^ ((ra >> 1) & 3)) * 8)];
            bf[i] = *(const f16x8*)&Bs[rb*32 + ((quad ^ ((rb >> 1) & 3)) * 8)];
        }
#pragma unroll
        for (int i = 0; i < 4; i++)
#pragma unroll
            for (int j = 0; j < 4; j++)
                acc[i][j] = __builtin_amdgcn_mfma_f32_16x16x32_f16(af[i], bf[j], acc[i][j], 0, 0, 0);
        __syncthreads();
    }
#pragma unroll
    for (int i = 0; i < 4; i++)
#pragma unroll
        for (int j = 0; j < 4; j++) {
            const int col = n0 + wn + j*16 + lane15;
#pragma unroll
            for (int r = 0; r < 4; r++) {
                const int row = m0 + wm + i*16 + quad*4 + r;
                Cout[(size_t)row*N + col] = acc[i][j][r] * scale;
            }
        }
}

// ---------------------------------------------------------------------------
// RoPE angle table via fp64 sincos. grid 4096 x 64
// ---------------------------------------------------------------------------
__global__ void rope_table(const int* __restrict__ pos,
                           float* __restrict__ ct, float* __restrict__ st_)
{
    const int r = blockIdx.x, i = threadIdx.x;
    double inv = exp2(-(double)i * (13.287712379549449 / 64.0)); // 10000^(-i/64)
    double a = (double)pos[r] * inv;
    double sd, cd;
    sincos(a, &sd, &cd);
    ct[r*64+i] = (float)cd;
    st_[r*64+i] = (float)sd;
}

// ---------------------------------------------------------------------------
// mask int32 -> bitset. grid 1024 x 256
// ---------------------------------------------------------------------------
__global__ __launch_bounds__(256) void mask_pack(const int* __restrict__ m,
                                                 u32* __restrict__ bits)
{
    const int g = blockIdx.x*256 + threadIdx.x;
    const int* p = m + (size_t)g*32;
    u32 w = 0;
#pragma unroll
    for (int j = 0; j < 8; j++) {
        int4 v = *(const int4*)&p[j*4];
        w |= (v.x!=0 ? 1u:0u) << (j*4+0);
        w |= (v.y!=0 ? 1u:0u) << (j*4+1);
        w |= (v.z!=0 ? 1u:0u) << (j*4+2);
        w |= (v.w!=0 ? 1u:0u) << (j*4+3);
    }
    bits[g] = w;
}

// ---------------------------------------------------------------------------
// RMSNorm(full 2048) + neox RoPE + k_bias, in-place on f16 Q,K. 1 block/row.
// ---------------------------------------------------------------------------
__global__ __launch_bounds__(256) void norm_rope(
    f16* __restrict__ Q, f16* __restrict__ K,
    const float* __restrict__ qw, const float* __restrict__ kw,
    const float* __restrict__ kb,
    const float* __restrict__ ct, const float* __restrict__ st_)
{
    const int r = blockIdx.x;
    const int t = threadIdx.x;
    const size_t base = (size_t)r * HID_;

    const int p0 = t * 4;
    const int hh = p0 >> 6;
    const int i0 = p0 & 63;
    const int c1 = hh * 128 + i0;
    f16x4 q1h = *(f16x4*)&Q[base + c1];
    f16x4 q2h = *(f16x4*)&Q[base + c1 + 64];
    f16x4 k1h = *(f16x4*)&K[base + c1];
    f16x4 k2h = *(f16x4*)&K[base + c1 + 64];
    float q1[4], q2[4], k1[4], k2[4];
#pragma unroll
    for (int j = 0; j < 4; j++) {
        q1[j]=(float)q1h[j]; q2[j]=(float)q2h[j];
        k1[j]=(float)k1h[j]; k2[j]=(float)k2h[j];
    }

    float ssq = 0.f, ssk = 0.f;
#pragma unroll
    for (int j = 0; j < 4; j++) {
        ssq += q1[j]*q1[j] + q2[j]*q2[j];
        ssk += k1[j]*k1[j] + k2[j]*k2[j];
    }
#pragma unroll
    for (int off = 1; off < 64; off <<= 1) {
        ssq += __shfl_xor(ssq, off);
        ssk += __shfl_xor(ssk, off);
    }
    __shared__ float rq[4], rk[4];
    const int wave = t >> 6, lane = t & 63;
    if (lane == 0) { rq[wave] = ssq; rk[wave] = ssk; }
    __syncthreads();
    ssq = rq[0] + rq[1] + rq[2] + rq[3];
    ssk = rk[0] + rk[1] + rk[2] + rk[3];
    const float rsq = rsqrtf(ssq * (1.f / HID_) + 1e-6f);
    const float rsk = rsqrtf(ssk * (1.f / HID_) + 1e-6f);

    float4 cos4 = *(const float4*)&ct[r*64 + i0];
    float4 sin4 = *(const float4*)&st_[r*64 + i0];
    float cc[4] = {cos4.x, cos4.y, cos4.z, cos4.w};
    float ss[4] = {sin4.x, sin4.y, sin4.z, sin4.w};

    f16x4 oq1, oq2, ok1, ok2;
#pragma unroll
    for (int j = 0; j < 4; j++) {
        const float c = cc[j], s = ss[j];
        const float wq1 = 1.f + qw[c1 + j], wq2 = 1.f + qw[c1 + 64 + j];
        const float wk1 = 1.f + kw[c1 + j], wk2 = 1.f + kw[c1 + 64 + j];
        float qa = q1[j] * rsq * wq1, qb = q2[j] * rsq * wq2;
        oq1[j] = (f16)(qa * c - qb * s);
        oq2[j] = (f16)(qb * c + qa * s);
        float ka = k1[j] * rsk * wk1, kbv = k2[j] * rsk * wk2;
        ok1[j] = (f16)(ka * c - kbv * s + kb[c1 + j]);
        ok2[j] = (f16)(kbv * c + ka * s + kb[c1 + 64 + j]);
    }
    *(f16x4*)&Q[base + c1]      = oq1;
    *(f16x4*)&Q[base + c1 + 64] = oq2;
    *(f16x4*)&K[base + c1]      = ok1;
    *(f16x4*)&K[base + c1 + 64] = ok2;
}

// ---------------------------------------------------------------------------
// MFMA flash attention, double-buffered global_load_lds pipeline. (unchanged)
// ---------------------------------------------------------------------------
__global__ __launch_bounds__(256, 2) void flash16(
    const f16* __restrict__ Qh, const f16* __restrict__ Kh,
    const f16* __restrict__ Vtg, const u32* __restrict__ bits,
    f16* __restrict__ AOh)
{
    __shared__ f16 lds[40960];   // 80 KiB

    const int t = threadIdx.x;
    const int w = t >> 6, l = t & 63;
    const int lane15 = l & 15, quad = l >> 4;
    const int bh = blockIdx.y;
    const int b = bh >> 4, h = bh & 15;
    const int q0 = blockIdx.x * 128;

    const size_t qkbase = ((size_t)(b*L_))*HID_ + h*128;   // Q/K row base
    const size_t vbase  = ((size_t)(bh*128))*L_;           // Vt row base

    // ---- stage Q tile into lds[0..16384) as swizzled [128][128]
#pragma unroll
    for (int i = 0; i < 8; i++) {
        int f = t + i*256;                 // 16B slot 0..2047
        int row = f >> 4, c4 = f & 15;
        int c = c4 ^ (row & 15);
        *(uint4*)&lds[row*128 + c4*8] =
            *(const uint4*)&Qh[qkbase + (size_t)(q0 + row)*HID_ + c*8];
    }
    __syncthreads();
    f16x8 qf[2][4];
#pragma unroll
    for (int qt = 0; qt < 2; qt++)
#pragma unroll
        for (int dc = 0; dc < 4; dc++)
            qf[qt][dc] = *(const f16x8*)&lds[(w*32 + qt*16 + lane15)*128
                                             + (((dc*4 + quad) ^ lane15) * 8)];
    __syncthreads();   // Q area about to be overwritten by K prefetch

    // ---- prefetch tile 0 into buffer 0
    {
        f16* Kb = lds;            f16* Vb = lds + 16384;
#pragma unroll
        for (int it = 0; it < 4; it++) {
            int j = w*256 + it*64 + l;      // 0..1023
            int krow = j >> 4, kc = (j & 15) ^ (krow & 15);
            gload_lds16(Kh + qkbase + (size_t)krow*HID_ + kc*8, Kb + j*8);
            int vrow = j >> 3, vc = (j & 7) ^ (vrow & 7);
            gload_lds16(Vtg + vbase + (size_t)vrow*L_ + vc*8, Vb + j*8);
        }
    }

    f32x4 oacc[2][8] = {};
    float lsum[2] = {0.f, 0.f};

    for (int kt = 0; kt < 32; kt++) {
        const int k0 = kt * 64;
        __syncthreads();   // drains vmcnt(0): tile kt DMA visible

        if (kt + 1 < 32) {
            const int kn = k0 + 64;
            f16* Kb = lds + ((kt+1) & 1)*8192;
            f16* Vb = lds + 16384 + ((kt+1) & 1)*8192;
#pragma unroll
            for (int it = 0; it < 4; it++) {
                int j = w*256 + it*64 + l;
                int krow = j >> 4, kc = (j & 15) ^ (krow & 15);
                gload_lds16(Kh + qkbase + (size_t)(kn + krow)*HID_ + kc*8, Kb + j*8);
                int vrow = j >> 3, vc = (j & 7) ^ (vrow & 7);
                gload_lds16(Vtg + vbase + (size_t)vrow*L_ + kn + vc*8, Vb + j*8);
            }
        }
        const f16* Kb = lds + (kt & 1)*8192;
        const f16* Vb = lds + 16384 + (kt & 1)*8192;
        f16* Ps = lds + 32768;

        u32 mw[2][2];
#pragma unroll
        for (int qt = 0; qt < 2; qt++) {
            int qrow = q0 + w*32 + qt*16 + lane15;
            const u32* bp = bits + (((size_t)(b*L_ + qrow)) << 6) + (k0 >> 5);
            mw[qt][0] = bp[0];
            mw[qt][1] = bp[1];
        }

        // ---- S^T = K * Q^T
        f32x4 st[2][4];
#pragma unroll
        for (int kt2 = 0; kt2 < 4; kt2++) {
            f16x8 kf[4];
#pragma unroll
            for (int dc = 0; dc < 4; dc++)
                kf[dc] = *(const f16x8*)&Kb[(kt2*16 + lane15)*128
                                            + (((dc*4 + quad) ^ lane15) * 8)];
#pragma unroll
            for (int qt = 0; qt < 2; qt++) {
                f32x4 a = {0.f, 0.f, 0.f, 0.f};
#pragma unroll
                for (int dc = 0; dc < 4; dc++)
                    a = __builtin_amdgcn_mfma_f32_16x16x32_f16(kf[dc], qf[qt][dc], a, 0, 0, 0);
                st[qt][kt2] = a;
            }
        }

        // ---- poly soft-cap + mask + fixed-max exp, P -> LDS
#pragma unroll
        for (int qt = 0; qt < 2; qt++) {
            const int prow = (w*32 + qt*16 + lane15) * 64;
            float ls = 0.f;
#pragma unroll
            for (int kt2 = 0; kt2 < 4; kt2++) {
                const u32 w_ = mw[qt][kt2 >> 1];
                f16x4 ph;
#pragma unroll
                for (int r = 0; r < 4; r++) {
                    float x = st[qt][kt2][r];
                    float y = x * x;
                    float p5 = fmaf(CAP_C2, y, CAP_C1);
                    float wv = fmaf(p5, y, CAP_C0);
                    float e = fmaf(x, wv, -FIXED_M2);
                    int kk = kt2*16 + quad*4 + r;
                    e = ((w_ >> (kk & 31)) & 1u) ? e : -150.f;
                    float pv = fexp2(e);
                    ls += pv;
                    ph[r] = (f16)pv;
                }
                const int c16s = (kt2*2 + (quad >> 1)) ^ (lane15 & 7);
                *(f16x4*)&Ps[prow + c16s*8 + (quad & 1)*4] = ph;
            }
            lsum[qt] += ls;
        }
        // no barrier: PV reads only this wave's own Ps rows (in-order DS)

        // ---- O += P * V
        f16x8 pf[2][2];
#pragma unroll
        for (int qt = 0; qt < 2; qt++)
#pragma unroll
            for (int c = 0; c < 2; c++)
                pf[qt][c] = *(const f16x8*)&Ps[(w*32 + qt*16 + lane15)*64
                                               + (((c*4 + quad) ^ (lane15 & 7)) * 8)];
#pragma unroll
        for (int dt = 0; dt < 8; dt++) {
            f16x8 vf[2];
#pragma unroll
            for (int c = 0; c < 2; c++)
                vf[c] = *(const f16x8*)&Vb[(dt*16 + lane15)*64
                                           + (((c*4 + quad) ^ (lane15 & 7)) * 8)];
#pragma unroll
            for (int qt = 0; qt < 2; qt++)
#pragma unroll
                for (int c = 0; c < 2; c++)
                    oacc[qt][dt] = __builtin_amdgcn_mfma_f32_16x16x32_f16(pf[qt][c], vf[c], oacc[qt][dt], 0, 0, 0);
        }
    }

    // ---- epilogue: l-reduce over quads, divide, store via LDS repack
#pragma unroll
    for (int qt = 0; qt < 2; qt++) {
        lsum[qt] += __shfl_xor(lsum[qt], 16);
        lsum[qt] += __shfl_xor(lsum[qt], 32);
    }
    __syncthreads();   // all LDS reads done; reuse lds[0..17408) as Ot [128][136]
    f16* Ot = lds;
#pragma unroll
    for (int qt = 0; qt < 2; qt++) {
#pragma unroll
        for (int r = 0; r < 4; r++) {
            float inv = frcp(__shfl(lsum[qt], quad*4 + r));
            const int row = w*32 + qt*16 + quad*4 + r;
#pragma unroll
            for (int dt = 0; dt < 8; dt++)
                Ot[row*136 + dt*16 + lane15] = (f16)(oacc[qt][dt][r] * inv);
        }
    }
    __syncthreads();
#pragma unroll
    for (int i = 0; i < 8; i++) {
        int f = t + i*256;
        int row = f >> 4, ch = f & 15;
        *(uint4*)&AOh[qkbase + (size_t)(q0 + row)*HID_ + ch*8] =
            *(const uint4*)&Ot[row*136 + ch*8];
    }
}

// ---------------------------------------------------------------------------
extern "C" void kernel_launch(void* const* d_in, const int* in_sizes, int n_in,
                              void* d_out, int out_size, void* d_ws, size_t ws_size,
                              hipStream_t stream)
{
    const float* hs  = (const float*)d_in[0];
    const float* Wq  = (const float*)d_in[1];
    const float* Wk  = (const float*)d_in[2];
    const float* Wv  = (const float*)d_in[3];
    const float* Wo  = (const float*)d_in[4];
    const float* qw  = (const float*)d_in[5];
    const float* kw  = (const float*)d_in[6];
    const float* kb  = (const float*)d_in[7];
    const float* vb  = (const float*)d_in[8];
    const int*   pos = (const int*)d_in[9];
    const int*   mask = (const int*)d_in[10];
    float* out = (float*)d_out;

    char* W = (char*)d_ws;
    f16* hs16 = (f16*)(W);                     // 16.8 MB; later AOh
    f16* w16o = (f16*)(W + 16777216);          // 8.4 MB
    f16* w16q = (f16*)(W + 25165824);          // 8.4 MB
    f16* w16k = (f16*)(W + 33554432);          // 8.4 MB
    f16* w16v = (f16*)(W + 41943040);          // 8.4 MB; later ct/st/bits
    f16* Q16  = (f16*)(W + 50331648);          // 16.8 MB
    f16* K16  = (f16*)(W + 67108864);          // 16.8 MB
    f16* Vtg  = (f16*)(W + 83886080);          // 16.8 MB (V written transposed)
    float* ct  = (float*)(W + 41943040);
    float* st_ = (float*)(W + 41943040 + 1048576);
    u32*  bits = (u32*) (W + 41943040 + 2097152);
    f16* AOh = hs16;

    const int M = B_ * L_;          // 4096
    const int nHS = M * HID_;       // 8388608
    const int nW  = HID_ * HID_;    // 4194304

    cvt5<<<dim3(4096, 5), 256, 0, stream>>>(hs, Wq, Wk, Wv, Wo,
                                            hs16, w16q, w16k, w16v, w16o, nHS, nW);

    gemm8p_qkv<<<dim3(HID_/256, M/256, 3), 512, 0, stream>>>(
        hs16, w16q, w16k, w16v, Q16, K16, Vtg, vb, M, HID_, HID_, FAN_IN);

    rope_table<<<M, 64, 0, stream>>>(pos, ct, st_);
    mask_pack<<<1024, 256, 0, stream>>>(mask, bits);

    norm_rope<<<M, 256, 0, stream>>>(Q16, K16, qw, kw, kb, ct, st_);

    flash16<<<dim3(16, 32), 256, 0, stream>>>(Q16, K16, Vtg, bits, AOh);

    gemm16_f32out<<<dim3(HID_/128, M/128), 256, 0, stream>>>(
        AOh, w16o, out, M, HID_, HID_, FAN_IN);
}

// Round 4
// 455.761 us; speedup vs baseline: 1.0010x; 1.0010x over previous
//
#include <hip/hip_runtime.h>
#include <math.h>

#define B_  2
#define L_  2048
#define HID_ 2048
#define H_  16
#define D_  128
#define FAN_IN 0.02209708691207961f   // 1/sqrt(2048)
#define SM_SCALE 0.08838834764831845f // 1/sqrt(128)
#define LOG2E 1.4426950408889634

typedef _Float16 f16;
typedef unsigned int u32;
typedef __attribute__((ext_vector_type(4))) _Float16 f16x4;
typedef __attribute__((ext_vector_type(8))) _Float16 f16x8;
typedef __attribute__((ext_vector_type(4))) float f32x4;

// soft-cap poly in log2 domain: f(x) = 30*tanh(x*SM_SCALE/30)*LOG2E
#define CAP_C0 0.12751738960681625f
#define CAP_C1 (-3.690028637e-7f)
#define CAP_C2 (1.28121e-12f)
#define FIXED_M2 8.0f    // fixed softmax max in log2 units

__device__ __forceinline__ float fexp2(float x) {
#if __has_builtin(__builtin_amdgcn_exp2f)
    return __builtin_amdgcn_exp2f(x);
#else
    return exp2f(x);
#endif
}
__device__ __forceinline__ float frcp(float x) {
#if __has_builtin(__builtin_amdgcn_rcpf)
    return __builtin_amdgcn_rcpf(x);
#else
    return 1.0f / x;
#endif
}
__device__ __forceinline__ void gload_lds16(const void* g, void* l) {
#if __has_builtin(__builtin_amdgcn_global_load_lds)
    __builtin_amdgcn_global_load_lds(
        (const __attribute__((address_space(1))) u32*)g,
        (__attribute__((address_space(3))) u32*)l, 16, 0, 0);
#else
    *(uint4*)l = *(const uint4*)g;
#endif
}

// ---------------------------------------------------------------------------
// fp32 -> f16 conversion for hs + 4 weight matrices.  grid (4096, 5)
// ---------------------------------------------------------------------------
__global__ __launch_bounds__(256) void cvt5(
    const float* __restrict__ s0, const float* __restrict__ s1,
    const float* __restrict__ s2, const float* __restrict__ s3,
    const float* __restrict__ s4,
    f16* __restrict__ d0, f16* __restrict__ d1, f16* __restrict__ d2,
    f16* __restrict__ d3, f16* __restrict__ d4, int n0, int nw)
{
    const int seg = blockIdx.y;
    const float* s = seg==0?s0:seg==1?s1:seg==2?s2:seg==3?s3:s4;
    f16* d = seg==0?d0:seg==1?d1:seg==2?d2:seg==3?d3:d4;
    const int n = (seg==0) ? n0 : nw;
    const int i = (blockIdx.x*256 + threadIdx.x)*8;
    if (i >= n) return;
    float4 a = *(const float4*)&s[i];
    float4 b = *(const float4*)&s[i+4];
    f16x8 o;
    o[0]=(f16)a.x; o[1]=(f16)a.y; o[2]=(f16)a.z; o[3]=(f16)a.w;
    o[4]=(f16)b.x; o[5]=(f16)b.y; o[6]=(f16)b.z; o[7]=(f16)b.w;
    *(f16x8*)&d[i] = o;
}

// ---------------------------------------------------------------------------
// Fused QKV GEMM, 256x128 tile / BK=32 / 4 waves / TRIPLE-buffered LDS
// (72 KiB) -> 2 blocks/CU co-resident.
//
// R2/R3 lesson (counters): at 1 block/CU with barrier-locked waves, the LDS
// window and MFMA window serialize exactly (iter = 4966 MFMA + 4608 LDS =
// measured 9564 cyc) regardless of source-level pipelining.  The mechanism
// that DOES overlap on this toolchain is cross-block wave-level overlap
// (m97/m114: 912 TF at 3 blocks/CU).  This kernel buys it: two unsynced
// blocks per CU + exact grid quantization (768 blocks = CUs stream 3
// half-tiles each, no idle round).
//
// Per K-step:  STAGE(kt+2 -> buf[(cur+2)%3]) ; ds_read frags(buf[cur]) ;
//              MFMA x32 ; s_waitcnt vmcnt(6) ; s_barrier
// Triple-buffer keeps one full K-step of DMA in flight across the barrier
// (vmcnt(6) drains tile kt+1, leaves kt+2's 6 loads pending -> DMA has a
// full iteration (~1200 cyc) to land, never latency-exposed).
// Hazards: WAR - buf[(cur+2)%3] was last read at iter kt-1; all its reads
// retired before that iter's MFMA cluster (lgkmcnt), hence before the
// barrier every wave passed before issuing this STAGE.  RAW - tile kt's
// loads drained by iter kt-1's vmcnt(6).  Tail: kt>=NT-2 stages nothing,
// waits vmcnt(0).
// Conflict-free LDS via the verified source-chunk XOR swizzle.
// QKV fused along N (cols 0..6143); T1 XCD-chunked tile swizzle (768%8==0).
// z==2 writes V transposed (Vt[bh][d][l]) with fp32 v_bias fused.
// ---------------------------------------------------------------------------
__global__ __launch_bounds__(256, 2) void gemm3b_qkv(
    const f16* __restrict__ A,
    const f16* __restrict__ Bq, const f16* __restrict__ Bk,
    const f16* __restrict__ Bv,
    f16* __restrict__ C0, f16* __restrict__ C1,
    f16* __restrict__ Vt, const float* __restrict__ vb,
    int M, int K, float scale)
{
    __shared__ f16 lds[36864];   // 72 KiB: 3 x (A[256][32] + B[128][32])

    // T1: XCD-chunked swizzle over 768 logical tiles; XCD k gets 96
    // consecutive tiles = 2 full A-panel rows (A-panel hot in XCD L2).
    const u32 lid = blockIdx.x + blockIdx.y * 48;      // 0..767
    const u32 swz = (lid & 7) * 96 + (lid >> 3);
    const int bx = (int)(swz % 48), by = (int)(swz / 48);
    const int m0  = by * 256;
    const int n0g = bx * 128;                 // global col in [0,6144)
    const int z   = n0g >> 11;
    const int n0z = n0g & 2047;
    const f16* Bw = z==0 ? Bq : z==1 ? Bk : Bv;

    const int t = threadIdx.x;                // 0..255
    const int w = t >> 6, l = t & 63;
    const int lane15 = l & 15, quad = l >> 4;
    const int wmr = (w >> 1) * 128;           // wave row block (0/128)
    const int wnc = (w & 1) * 64;             // wave col block (0/64)
    const int xslot = (quad ^ ((lane15 >> 1) & 3)) * 8;   // swizzled frag slot

    // staging: thread covers rows j*64 + (t>>2) (j load index), chunk t&3;
    // source chunk pre-swizzled (t&3)^((t>>3)&3) -- row>>1 & 3 is
    // j-independent since j*64>>1 ≡ 0 mod 4.  LDS dest lane-linear.
    const int srow = t >> 2;
    const int cs   = (((t & 3) ^ ((t >> 3) & 3))) * 8;
    const f16* Ag = A  + (size_t)(m0  + srow) * K + cs;
    const f16* Bg = Bw + (size_t)(n0z + srow) * K + cs;
    f16* const ldst = lds + t * 8;
    const size_t K64 = (size_t)64 * K;

#define STAGE(T, SB) {                                        \
    f16* d_ = ldst + (SB) * 12288;                            \
    const f16* a_ = Ag + (T) * 32;                            \
    gload_lds16(a_,           d_);                            \
    gload_lds16(a_ +   K64,   d_ + 2048);                     \
    gload_lds16(a_ + 2*K64,   d_ + 4096);                     \
    gload_lds16(a_ + 3*K64,   d_ + 6144);                     \
    const f16* b_ = Bg + (T) * 32;                            \
    gload_lds16(b_,           d_ + 8192);                     \
    gload_lds16(b_ +   K64,   d_ + 10240); }

    f32x4 acc[8][4] = {};

    // ---- prologue: tiles 0,1 staged; drain tile 0, keep tile 1 in flight
    STAGE(0, 0); STAGE(1, 1);
    asm volatile("s_waitcnt vmcnt(6)" ::: "memory");
    __builtin_amdgcn_s_barrier();

    int cur = 0;
    const int NT = K >> 5;   // 64
    for (int kt = 0; kt < NT; ++kt) {
        int sb = cur + 2; if (sb >= 3) sb -= 3;
        const bool pf = (kt + 2 < NT);
        if (pf) STAGE(kt + 2, sb);

        const f16* Ab = lds + cur * 12288;
        const f16* Bb = Ab + 8192;
        f16x8 af[8], bf[4];
#pragma unroll
        for (int fi = 0; fi < 8; fi++) {
            const int r = wmr + fi*16 + lane15;
            af[fi] = *(const f16x8*)&Ab[r*32 + xslot];
        }
#pragma unroll
        for (int j = 0; j < 4; j++) {
            const int r = wnc + j*16 + lane15;
            bf[j] = *(const f16x8*)&Bb[r*32 + xslot];
        }
        __builtin_amdgcn_s_setprio(1);
#pragma unroll
        for (int fi = 0; fi < 8; fi++)
#pragma unroll
            for (int j = 0; j < 4; j++)
                acc[fi][j] = __builtin_amdgcn_mfma_f32_16x16x32_f16(
                    af[fi], bf[j], acc[fi][j], 0, 0, 0);
        __builtin_amdgcn_s_setprio(0);

        if (pf) { asm volatile("s_waitcnt vmcnt(6)" ::: "memory"); }
        else    { asm volatile("s_waitcnt vmcnt(0)" ::: "memory"); }
        __builtin_amdgcn_s_barrier();
        cur = cur + 1; if (cur == 3) cur = 0;
    }
#undef STAGE

    if (z == 2) {
        // V: write transposed with bias.  out(row=b*L+l, col=h*128+d)
        // -> Vt[(b*16+h)*128 + d][l], f16x4 along l.
#pragma unroll
        for (int fi = 0; fi < 8; fi++)
#pragma unroll
            for (int j = 0; j < 4; j++) {
                const int cz = n0z + wnc + j*16 + lane15;
                const int row0 = m0 + wmr + fi*16 + quad*4;
                const int b = row0 >> 11, ll = row0 & 2047;
                const int bh = (b << 4) + (cz >> 7);
                const float bias = vb[cz];
                f16x4 ph;
#pragma unroll
                for (int r = 0; r < 4; r++)
                    ph[r] = (f16)(acc[fi][j][r] * scale + bias);
                *(f16x4*)&Vt[((size_t)(bh*128 + (cz & 127)))*(size_t)L_ + ll] = ph;
            }
    } else {
        f16* Cout = z==0 ? C0 : C1;
#pragma unroll
        for (int fi = 0; fi < 8; fi++)
#pragma unroll
            for (int j = 0; j < 4; j++) {
                const int cz = n0z + wnc + j*16 + lane15;
#pragma unroll
                for (int r = 0; r < 4; r++) {
                    const int row = m0 + wmr + fi*16 + quad*4 + r;
                    Cout[(size_t)row*HID_ + cz] = (f16)(acc[fi][j][r] * scale);
                }
            }
    }
}

// ---------------------------------------------------------------------------
// GEMM C[M,N] = scale * A[M,K] @ Bw[N,K]^T, f16 in, f32 out (final proj).
// 128² two-phase structure (unchanged this round).
// ---------------------------------------------------------------------------
__global__ __launch_bounds__(256) void gemm16_f32out(
    const f16* __restrict__ A, const f16* __restrict__ Bw,
    float* __restrict__ Cout, int M, int N, int K, float scale)
{
    __shared__ f16 As[128*32];
    __shared__ f16 Bs[128*32];
    const int t = threadIdx.x;
    const int w = t >> 6, l = t & 63;
    const int lane15 = l & 15, quad = l >> 4;
    const int m0 = blockIdx.y*128, n0 = blockIdx.x*128;
    const int wm = (w & 1)*64, wn = (w >> 1)*64;

    const int srow = t >> 2;
    const int scol = (((t & 3) ^ ((t >> 3) & 3))) * 8;
    const f16* Ag = A  + (size_t)(m0 + srow)*K + scol;
    const f16* Bg = Bw + (size_t)(n0 + srow)*K + scol;
    f16* Al = As + t*8;
    f16* Bl = Bs + t*8;

    f32x4 acc[4][4] = {};
    for (int k0 = 0; k0 < K; k0 += 32) {
        gload_lds16(Ag + k0,                 Al);
        gload_lds16(Ag + (size_t)64*K + k0,  Al + 2048);
        gload_lds16(Bg + k0,                 Bl);
        gload_lds16(Bg + (size_t)64*K + k0,  Bl + 2048);
        __syncthreads();
        f16x8 af[4], bf[4];
#pragma unroll
        for (int i = 0; i < 4; i++) {
            const int ra = wm + i*16 + lane15;
            const int rb = wn + i*16 + lane15;
            af[i] = *(const f16x8*)&As[ra*32 + ((quad ^ ((ra >> 1) & 3)) * 8)];
            bf[i] = *(const f16x8*)&Bs[rb*32 + ((quad ^ ((rb >> 1) & 3)) * 8)];
        }
#pragma unroll
        for (int i = 0; i < 4; i++)
#pragma unroll
            for (int j = 0; j < 4; j++)
                acc[i][j] = __builtin_amdgcn_mfma_f32_16x16x32_f16(af[i], bf[j], acc[i][j], 0, 0, 0);
        __syncthreads();
    }
#pragma unroll
    for (int i = 0; i < 4; i++)
#pragma unroll
        for (int j = 0; j < 4; j++) {
            const int col = n0 + wn + j*16 + lane15;
#pragma unroll
            for (int r = 0; r < 4; r++) {
                const int row = m0 + wm + i*16 + quad*4 + r;
                Cout[(size_t)row*N + col] = acc[i][j][r] * scale;
            }
        }
}

// ---------------------------------------------------------------------------
// RoPE angle table via fp64 sincos. grid 4096 x 64
// ---------------------------------------------------------------------------
__global__ void rope_table(const int* __restrict__ pos,
                           float* __restrict__ ct, float* __restrict__ st_)
{
    const int r = blockIdx.x, i = threadIdx.x;
    double inv = exp2(-(double)i * (13.287712379549449 / 64.0)); // 10000^(-i/64)
    double a = (double)pos[r] * inv;
    double sd, cd;
    sincos(a, &sd, &cd);
    ct[r*64+i] = (float)cd;
    st_[r*64+i] = (float)sd;
}

// ---------------------------------------------------------------------------
// mask int32 -> bitset. grid 1024 x 256
// ---------------------------------------------------------------------------
__global__ __launch_bounds__(256) void mask_pack(const int* __restrict__ m,
                                                 u32* __restrict__ bits)
{
    const int g = blockIdx.x*256 + threadIdx.x;
    const int* p = m + (size_t)g*32;
    u32 w = 0;
#pragma unroll
    for (int j = 0; j < 8; j++) {
        int4 v = *(const int4*)&p[j*4];
        w |= (v.x!=0 ? 1u:0u) << (j*4+0);
        w |= (v.y!=0 ? 1u:0u) << (j*4+1);
        w |= (v.z!=0 ? 1u:0u) << (j*4+2);
        w |= (v.w!=0 ? 1u:0u) << (j*4+3);
    }
    bits[g] = w;
}

// ---------------------------------------------------------------------------
// RMSNorm(full 2048) + neox RoPE + k_bias, in-place on f16 Q,K. 1 block/row.
// ---------------------------------------------------------------------------
__global__ __launch_bounds__(256) void norm_rope(
    f16* __restrict__ Q, f16* __restrict__ K,
    const float* __restrict__ qw, const float* __restrict__ kw,
    const float* __restrict__ kb,
    const float* __restrict__ ct, const float* __restrict__ st_)
{
    const int r = blockIdx.x;
    const int t = threadIdx.x;
    const size_t base = (size_t)r * HID_;

    const int p0 = t * 4;
    const int hh = p0 >> 6;
    const int i0 = p0 & 63;
    const int c1 = hh * 128 + i0;
    f16x4 q1h = *(f16x4*)&Q[base + c1];
    f16x4 q2h = *(f16x4*)&Q[base + c1 + 64];
    f16x4 k1h = *(f16x4*)&K[base + c1];
    f16x4 k2h = *(f16x4*)&K[base + c1 + 64];
    float q1[4], q2[4], k1[4], k2[4];
#pragma unroll
    for (int j = 0; j < 4; j++) {
        q1[j]=(float)q1h[j]; q2[j]=(float)q2h[j];
        k1[j]=(float)k1h[j]; k2[j]=(float)k2h[j];
    }

    float ssq = 0.f, ssk = 0.f;
#pragma unroll
    for (int j = 0; j < 4; j++) {
        ssq += q1[j]*q1[j] + q2[j]*q2[j];
        ssk += k1[j]*k1[j] + k2[j]*k2[j];
    }
#pragma unroll
    for (int off = 1; off < 64; off <<= 1) {
        ssq += __shfl_xor(ssq, off);
        ssk += __shfl_xor(ssk, off);
    }
    __shared__ float rq[4], rk[4];
    const int wave = t >> 6, lane = t & 63;
    if (lane == 0) { rq[wave] = ssq; rk[wave] = ssk; }
    __syncthreads();
    ssq = rq[0] + rq[1] + rq[2] + rq[3];
    ssk = rk[0] + rk[1] + rk[2] + rk[3];
    const float rsq = rsqrtf(ssq * (1.f / HID_) + 1e-6f);
    const float rsk = rsqrtf(ssk * (1.f / HID_) + 1e-6f);

    float4 cos4 = *(const float4*)&ct[r*64 + i0];
    float4 sin4 = *(const float4*)&st_[r*64 + i0];
    float cc[4] = {cos4.x, cos4.y, cos4.z, cos4.w};
    float ss[4] = {sin4.x, sin4.y, sin4.z, sin4.w};

    f16x4 oq1, oq2, ok1, ok2;
#pragma unroll
    for (int j = 0; j < 4; j++) {
        const float c = cc[j], s = ss[j];
        const float wq1 = 1.f + qw[c1 + j], wq2 = 1.f + qw[c1 + 64 + j];
        const float wk1 = 1.f + kw[c1 + j], wk2 = 1.f + kw[c1 + 64 + j];
        float qa = q1[j] * rsq * wq1, qb = q2[j] * rsq * wq2;
        oq1[j] = (f16)(qa * c - qb * s);
        oq2[j] = (f16)(qb * c + qa * s);
        float ka = k1[j] * rsk * wk1, kbv = k2[j] * rsk * wk2;
        ok1[j] = (f16)(ka * c - kbv * s + kb[c1 + j]);
        ok2[j] = (f16)(kbv * c + ka * s + kb[c1 + 64 + j]);
    }
    *(f16x4*)&Q[base + c1]      = oq1;
    *(f16x4*)&Q[base + c1 + 64] = oq2;
    *(f16x4*)&K[base + c1]      = ok1;
    *(f16x4*)&K[base + c1 + 64] = ok2;
}

// ---------------------------------------------------------------------------
// MFMA flash attention, double-buffered global_load_lds pipeline. (unchanged)
// ---------------------------------------------------------------------------
__global__ __launch_bounds__(256, 2) void flash16(
    const f16* __restrict__ Qh, const f16* __restrict__ Kh,
    const f16* __restrict__ Vtg, const u32* __restrict__ bits,
    f16* __restrict__ AOh)
{
    __shared__ f16 lds[40960];   // 80 KiB

    const int t = threadIdx.x;
    const int w = t >> 6, l = t & 63;
    const int lane15 = l & 15, quad = l >> 4;
    const int bh = blockIdx.y;
    const int b = bh >> 4, h = bh & 15;
    const int q0 = blockIdx.x * 128;

    const size_t qkbase = ((size_t)(b*L_))*HID_ + h*128;   // Q/K row base
    const size_t vbase  = ((size_t)(bh*128))*L_;           // Vt row base

    // ---- stage Q tile into lds[0..16384) as swizzled [128][128]
#pragma unroll
    for (int i = 0; i < 8; i++) {
        int f = t + i*256;                 // 16B slot 0..2047
        int row = f >> 4, c4 = f & 15;
        int c = c4 ^ (row & 15);
        *(uint4*)&lds[row*128 + c4*8] =
            *(const uint4*)&Qh[qkbase + (size_t)(q0 + row)*HID_ + c*8];
    }
    __syncthreads();
    f16x8 qf[2][4];
#pragma unroll
    for (int qt = 0; qt < 2; qt++)
#pragma unroll
        for (int dc = 0; dc < 4; dc++)
            qf[qt][dc] = *(const f16x8*)&lds[(w*32 + qt*16 + lane15)*128
                                             + (((dc*4 + quad) ^ lane15) * 8)];
    __syncthreads();   // Q area about to be overwritten by K prefetch

    // ---- prefetch tile 0 into buffer 0
    {
        f16* Kb = lds;            f16* Vb = lds + 16384;
#pragma unroll
        for (int it = 0; it < 4; it++) {
            int j = w*256 + it*64 + l;      // 0..1023
            int krow = j >> 4, kc = (j & 15) ^ (krow & 15);
            gload_lds16(Kh + qkbase + (size_t)krow*HID_ + kc*8, Kb + j*8);
            int vrow = j >> 3, vc = (j & 7) ^ (vrow & 7);
            gload_lds16(Vtg + vbase + (size_t)vrow*L_ + vc*8, Vb + j*8);
        }
    }

    f32x4 oacc[2][8] = {};
    float lsum[2] = {0.f, 0.f};

    for (int kt = 0; kt < 32; kt++) {
        const int k0 = kt * 64;
        __syncthreads();   // drains vmcnt(0): tile kt DMA visible

        if (kt + 1 < 32) {
            const int kn = k0 + 64;
            f16* Kb = lds + ((kt+1) & 1)*8192;
            f16* Vb = lds + 16384 + ((kt+1) & 1)*8192;
#pragma unroll
            for (int it = 0; it < 4; it++) {
                int j = w*256 + it*64 + l;
                int krow = j >> 4, kc = (j & 15) ^ (krow & 15);
                gload_lds16(Kh + qkbase + (size_t)(kn + krow)*HID_ + kc*8, Kb + j*8);
                int vrow = j >> 3, vc = (j & 7) ^ (vrow & 7);
                gload_lds16(Vtg + vbase + (size_t)vrow*L_ + kn + vc*8, Vb + j*8);
            }
        }
        const f16* Kb = lds + (kt & 1)*8192;
        const f16* Vb = lds + 16384 + (kt & 1)*8192;
        f16* Ps = lds + 32768;

        u32 mw[2][2];
#pragma unroll
        for (int qt = 0; qt < 2; qt++) {
            int qrow = q0 + w*32 + qt*16 + lane15;
            const u32* bp = bits + (((size_t)(b*L_ + qrow)) << 6) + (k0 >> 5);
            mw[qt][0] = bp[0];
            mw[qt][1] = bp[1];
        }

        // ---- S^T = K * Q^T
        f32x4 st[2][4];
#pragma unroll
        for (int kt2 = 0; kt2 < 4; kt2++) {
            f16x8 kf[4];
#pragma unroll
            for (int dc = 0; dc < 4; dc++)
                kf[dc] = *(const f16x8*)&Kb[(kt2*16 + lane15)*128
                                            + (((dc*4 + quad) ^ lane15) * 8)];
#pragma unroll
            for (int qt = 0; qt < 2; qt++) {
                f32x4 a = {0.f, 0.f, 0.f, 0.f};
#pragma unroll
                for (int dc = 0; dc < 4; dc++)
                    a = __builtin_amdgcn_mfma_f32_16x16x32_f16(kf[dc], qf[qt][dc], a, 0, 0, 0);
                st[qt][kt2] = a;
            }
        }

        // ---- poly soft-cap + mask + fixed-max exp, P -> LDS
#pragma unroll
        for (int qt = 0; qt < 2; qt++) {
            const int prow = (w*32 + qt*16 + lane15) * 64;
            float ls = 0.f;
#pragma unroll
            for (int kt2 = 0; kt2 < 4; kt2++) {
                const u32 w_ = mw[qt][kt2 >> 1];
                f16x4 ph;
#pragma unroll
                for (int r = 0; r < 4; r++) {
                    float x = st[qt][kt2][r];
                    float y = x * x;
                    float p5 = fmaf(CAP_C2, y, CAP_C1);
                    float wv = fmaf(p5, y, CAP_C0);
                    float e = fmaf(x, wv, -FIXED_M2);
                    int kk = kt2*16 + quad*4 + r;
                    e = ((w_ >> (kk & 31)) & 1u) ? e : -150.f;
                    float pv = fexp2(e);
                    ls += pv;
                    ph[r] = (f16)pv;
                }
                const int c16s = (kt2*2 + (quad >> 1)) ^ (lane15 & 7);
                *(f16x4*)&Ps[prow + c16s*8 + (quad & 1)*4] = ph;
            }
            lsum[qt] += ls;
        }
        // no barrier: PV reads only this wave's own Ps rows (in-order DS)

        // ---- O += P * V
        f16x8 pf[2][2];
#pragma unroll
        for (int qt = 0; qt < 2; qt++)
#pragma unroll
            for (int c = 0; c < 2; c++)
                pf[qt][c] = *(const f16x8*)&Ps[(w*32 + qt*16 + lane15)*64
                                               + (((c*4 + quad) ^ (lane15 & 7)) * 8)];
#pragma unroll
        for (int dt = 0; dt < 8; dt++) {
            f16x8 vf[2];
#pragma unroll
            for (int c = 0; c < 2; c++)
                vf[c] = *(const f16x8*)&Vb[(dt*16 + lane15)*64
                                           + (((c*4 + quad) ^ (lane15 & 7)) * 8)];
#pragma unroll
            for (int qt = 0; qt < 2; qt++)
#pragma unroll
                for (int c = 0; c < 2; c++)
                    oacc[qt][dt] = __builtin_amdgcn_mfma_f32_16x16x32_f16(pf[qt][c], vf[c], oacc[qt][dt], 0, 0, 0);
        }
    }

    // ---- epilogue: l-reduce over quads, divide, store via LDS repack
#pragma unroll
    for (int qt = 0; qt < 2; qt++) {
        lsum[qt] += __shfl_xor(lsum[qt], 16);
        lsum[qt] += __shfl_xor(lsum[qt], 32);
    }
    __syncthreads();   // all LDS reads done; reuse lds[0..17408) as Ot [128][136]
    f16* Ot = lds;
#pragma unroll
    for (int qt = 0; qt < 2; qt++) {
#pragma unroll
        for (int r = 0; r < 4; r++) {
            float inv = frcp(__shfl(lsum[qt], quad*4 + r));
            const int row = w*32 + qt*16 + quad*4 + r;
#pragma unroll
            for (int dt = 0; dt < 8; dt++)
                Ot[row*136 + dt*16 + lane15] = (f16)(oacc[qt][dt][r] * inv);
        }
    }
    __syncthreads();
#pragma unroll
    for (int i = 0; i < 8; i++) {
        int f = t + i*256;
        int row = f >> 4, ch = f & 15;
        *(uint4*)&AOh[qkbase + (size_t)(q0 + row)*HID_ + ch*8] =
            *(const uint4*)&Ot[row*136 + ch*8];
    }
}

// ---------------------------------------------------------------------------
extern "C" void kernel_launch(void* const* d_in, const int* in_sizes, int n_in,
                              void* d_out, int out_size, void* d_ws, size_t ws_size,
                              hipStream_t stream)
{
    const float* hs  = (const float*)d_in[0];
    const float* Wq  = (const float*)d_in[1];
    const float* Wk  = (const float*)d_in[2];
    const float* Wv  = (const float*)d_in[3];
    const float* Wo  = (const float*)d_in[4];
    const float* qw  = (const float*)d_in[5];
    const float* kw  = (const float*)d_in[6];
    const float* kb  = (const float*)d_in[7];
    const float* vb  = (const float*)d_in[8];
    const int*   pos = (const int*)d_in[9];
    const int*   mask = (const int*)d_in[10];
    float* out = (float*)d_out;

    char* W = (char*)d_ws;
    f16* hs16 = (f16*)(W);                     // 16.8 MB; later AOh
    f16* w16o = (f16*)(W + 16777216);          // 8.4 MB
    f16* w16q = (f16*)(W + 25165824);          // 8.4 MB
    f16* w16k = (f16*)(W + 33554432);          // 8.4 MB
    f16* w16v = (f16*)(W + 41943040);          // 8.4 MB; later ct/st/bits
    f16* Q16  = (f16*)(W + 50331648);          // 16.8 MB
    f16* K16  = (f16*)(W + 67108864);          // 16.8 MB
    f16* Vtg  = (f16*)(W + 83886080);          // 16.8 MB (V written transposed)
    float* ct  = (float*)(W + 41943040);
    float* st_ = (float*)(W + 41943040 + 1048576);
    u32*  bits = (u32*) (W + 41943040 + 2097152);
    f16* AOh = hs16;

    const int M = B_ * L_;          // 4096
    const int nHS = M * HID_;       // 8388608
    const int nW  = HID_ * HID_;    // 4194304

    cvt5<<<dim3(4096, 5), 256, 0, stream>>>(hs, Wq, Wk, Wv, Wo,
                                            hs16, w16q, w16k, w16v, w16o, nHS, nW);

    gemm3b_qkv<<<dim3(48, 16), 256, 0, stream>>>(
        hs16, w16q, w16k, w16v, Q16, K16, Vtg, vb, M, HID_, FAN_IN);

    rope_table<<<M, 64, 0, stream>>>(pos, ct, st_);
    mask_pack<<<1024, 256, 0, stream>>>(mask, bits);

    norm_rope<<<M, 256, 0, stream>>>(Q16, K16, qw, kw, kb, ct, st_);

    flash16<<<dim3(16, 32), 256, 0, stream>>>(Q16, K16, Vtg, bits, AOh);

    gemm16_f32out<<<dim3(HID_/128, M/128), 256, 0, stream>>>(
        AOh, w16o, out, M, HID_, HID_, FAN_IN);
}

// Round 5
// 453.635 us; speedup vs baseline: 1.0057x; 1.0047x over previous
//
#include <hip/hip_runtime.h>
#include <math.h>

#define B_  2
#define L_  2048
#define HID_ 2048
#define H_  16
#define D_  128
#define FAN_IN 0.02209708691207961f   // 1/sqrt(2048)
#define SM_SCALE 0.08838834764831845f // 1/sqrt(128)
#define LOG2E 1.4426950408889634

typedef _Float16 f16;
typedef unsigned int u32;
typedef __attribute__((ext_vector_type(4))) _Float16 f16x4;
typedef __attribute__((ext_vector_type(8))) _Float16 f16x8;
typedef __attribute__((ext_vector_type(4))) float f32x4;

// soft-cap poly in log2 domain: f(x) = 30*tanh(x*SM_SCALE/30)*LOG2E
#define CAP_C0 0.12751738960681625f
#define CAP_C1 (-3.690028637e-7f)
#define CAP_C2 (1.28121e-12f)
#define FIXED_M2 8.0f    // fixed softmax max in log2 units

__device__ __forceinline__ float fexp2(float x) {
#if __has_builtin(__builtin_amdgcn_exp2f)
    return __builtin_amdgcn_exp2f(x);
#else
    return exp2f(x);
#endif
}
__device__ __forceinline__ float frcp(float x) {
#if __has_builtin(__builtin_amdgcn_rcpf)
    return __builtin_amdgcn_rcpf(x);
#else
    return 1.0f / x;
#endif
}
__device__ __forceinline__ void gload_lds16(const void* g, void* l) {
#if __has_builtin(__builtin_amdgcn_global_load_lds)
    __builtin_amdgcn_global_load_lds(
        (const __attribute__((address_space(1))) u32*)g,
        (__attribute__((address_space(3))) u32*)l, 16, 0, 0);
#else
    *(uint4*)l = *(const uint4*)g;
#endif
}

// ---------------------------------------------------------------------------
// fp32 -> f16 conversion for hs + 4 weight matrices.  grid (4096, 5)
// ---------------------------------------------------------------------------
__global__ __launch_bounds__(256) void cvt5(
    const float* __restrict__ s0, const float* __restrict__ s1,
    const float* __restrict__ s2, const float* __restrict__ s3,
    const float* __restrict__ s4,
    f16* __restrict__ d0, f16* __restrict__ d1, f16* __restrict__ d2,
    f16* __restrict__ d3, f16* __restrict__ d4, int n0, int nw)
{
    const int seg = blockIdx.y;
    const float* s = seg==0?s0:seg==1?s1:seg==2?s2:seg==3?s3:s4;
    f16* d = seg==0?d0:seg==1?d1:seg==2?d2:seg==3?d3:d4;
    const int n = (seg==0) ? n0 : nw;
    const int i = (blockIdx.x*256 + threadIdx.x)*8;
    if (i >= n) return;
    float4 a = *(const float4*)&s[i];
    float4 b = *(const float4*)&s[i+4];
    f16x8 o;
    o[0]=(f16)a.x; o[1]=(f16)a.y; o[2]=(f16)a.z; o[3]=(f16)a.w;
    o[4]=(f16)b.x; o[5]=(f16)b.y; o[6]=(f16)b.z; o[7]=(f16)b.w;
    *(f16x8*)&d[i] = o;
}

// ---------------------------------------------------------------------------
// Fused QKV GEMM — R2 kernel restored verbatim (best measured: 126.5 us).
// 256x256 tile / BK=64 / 8 waves, m201-style 8-phase iteration, one region
// staged per phase, uniform vmcnt(10) before odd phases.
// ---------------------------------------------------------------------------
__global__ __launch_bounds__(512, 2) void gemm8p_qkv(
    const f16* __restrict__ A,
    const f16* __restrict__ Bq, const f16* __restrict__ Bk,
    const f16* __restrict__ Bv,
    f16* __restrict__ C0, f16* __restrict__ C1,
    f16* __restrict__ Vt, const float* __restrict__ vb,
    int M, int N, int K, float scale)
{
    __shared__ f16 lds[65536];   // 128 KiB

    // T1: XCD-chunked tile swizzle.  lid 0..383; XCD k gets 48 consecutive
    // tile indices (same z, contiguous m-panels).
    const u32 lid = blockIdx.x + (blockIdx.y << 3) + (blockIdx.z << 7);
    const u32 swz = (lid & 7) * 48 + (lid >> 3);
    const int n0 = (swz & 7) * 256;
    const int m0 = ((swz >> 3) & 15) * 256;
    const int z  = swz >> 7;
    const f16* Bw = z==0 ? Bq : z==1 ? Bk : Bv;

    const int t = threadIdx.x;            // 0..511
    const int w = t >> 6, l = t & 63;
    const int lane15 = l & 15, quad = l >> 4;
    const int wmr = (w >> 2) * 128;       // wave row block (0/128)
    const int wnc = (w & 3) * 64;         // wave col block
    const int xslot = (quad ^ ((lane15 >> 1) & 3)) * 8;   // swizzled frag slot

    const int srow = t >> 2;
    const int sc   = t & 3;
    const int cs0 = (sc ^ ((srow >> 1) & 3)) * 8;
    const f16* Ag0 = A  + (size_t)(m0 + srow) * K + cs0;
    const f16* Ag1 = A  + (size_t)(m0 + 128 + srow) * K + cs0;
    const f16* Bg0 = Bw + (size_t)(n0 + srow) * K + cs0;
    const f16* Bg1 = Bw + (size_t)(n0 + 128 + srow) * K + cs0;
    f16* const ldst = lds + t * 8;

#define STG_A(BUF, S, KOFF) {                                             \
    gload_lds16(Ag0 + (KOFF), ldst + (BUF) + (S)*16384);                  \
    gload_lds16(Ag1 + (KOFF), ldst + (BUF) + (S)*16384 + 4096); }
#define STG_B(BUF, S, KOFF) {                                             \
    gload_lds16(Bg0 + (KOFF), ldst + (BUF) + (S)*16384 + 8192);           \
    gload_lds16(Bg1 + (KOFF), ldst + (BUF) + (S)*16384 + 12288); }
#define WV(N) asm volatile("s_waitcnt vmcnt(" #N ")" ::: "memory")
#define BAR() __builtin_amdgcn_s_barrier()

    f32x4 acc[8][4] = {};
    f16x8 bfr[4];

#define PHASE(BUFO, S, H, ...)                                            \
    {                                                                     \
        const f16* Ab_ = lds + (BUFO) + (S)*16384;                        \
        f16x8 af[4];                                                      \
        _Pragma("unroll")                                                 \
        for (int i = 0; i < 4; i++) {                                     \
            const int r = wmr + (H)*64 + i*16 + lane15;                   \
            af[i] = *(const f16x8*)&Ab_[r*32 + xslot];                    \
        }                                                                 \
        if ((H) == 0) {                                                   \
            const f16* Bb_ = Ab_ + 8192;                                  \
            _Pragma("unroll")                                             \
            for (int j = 0; j < 4; j++) {                                 \
                const int r = wnc + j*16 + lane15;                        \
                bfr[j] = *(const f16x8*)&Bb_[r*32 + xslot];               \
            }                                                             \
        }                                                                 \
        __VA_ARGS__;                                                      \
        __builtin_amdgcn_s_barrier();                                     \
        __builtin_amdgcn_s_setprio(1);                                    \
        _Pragma("unroll")                                                 \
        for (int i = 0; i < 4; i++)                                       \
            _Pragma("unroll")                                             \
            for (int j = 0; j < 4; j++)                                   \
                acc[(H)*4+i][j] = __builtin_amdgcn_mfma_f32_16x16x32_f16( \
                    af[i], bfr[j], acc[(H)*4+i][j], 0, 0, 0);             \
        __builtin_amdgcn_s_setprio(0);                                    \
    }

    // ---- prologue: tile 0 (4 regions) + tile 1 (B0,A0,B1) = 14 loads
    STG_B(0, 0, 0);  STG_A(0, 0, 0);  STG_B(0, 1, 32);  STG_A(0, 1, 32);
    STG_B(32768, 0, 64);  STG_A(32768, 0, 64);  STG_B(32768, 1, 96);
    WV(10); BAR();

    const int NIT = (K >> 7) - 1;   // 15
    for (int it = 0; it < NIT; ++it) {
        const int kB = it * 128;
        const int k1A = kB + 96;          // tile 2it+1, ksub1
        const int kE  = kB + 128;         // tile 2it+2
        const int kO  = kB + 192;         // tile 2it+3

        PHASE(0,     0, 0, STG_A(32768, 1, k1A))        // P1
        BAR();
        PHASE(0,     0, 1, STG_B(0,     0, kE))         // P2
        WV(10); BAR();
        PHASE(0,     1, 0, STG_A(0,     0, kE))         // P3
        BAR();
        PHASE(0,     1, 1, STG_B(0,     1, kE + 32))    // P4
        WV(10); BAR();
        PHASE(32768, 0, 0, STG_A(0,     1, kE + 32))    // P5
        BAR();
        PHASE(32768, 0, 1, STG_B(32768, 0, kO))         // P6
        WV(10); BAR();
        PHASE(32768, 1, 0, STG_A(32768, 0, kO))         // P7
        BAR();
        PHASE(32768, 1, 1, STG_B(32768, 1, kO + 32))    // P8
        WV(10); BAR();
    }

    // ---- peeled last iter (K-tiles 30,31)
    {
        const int k1A = NIT * 128 + 96;                 // 2016
        PHASE(0,     0, 0, STG_A(32768, 1, k1A))        // P1
        BAR();
        PHASE(0,     0, 1, )                            // P2
        WV(8); BAR();
        PHASE(0,     1, 0, )                            // P3
        BAR();
        PHASE(0,     1, 1, )                            // P4
        WV(4); BAR();
        PHASE(32768, 0, 0, )                            // P5
        BAR();
        PHASE(32768, 0, 1, )                            // P6
        WV(0); BAR();
        PHASE(32768, 1, 0, )                            // P7
        BAR();
        PHASE(32768, 1, 1, )                            // P8
    }

#undef PHASE
#undef STG_A
#undef STG_B
#undef WV
#undef BAR

    if (z == 2) {
#pragma unroll
        for (int fi = 0; fi < 8; fi++)
#pragma unroll
            for (int j = 0; j < 4; j++) {
                const int col = n0 + wnc + j*16 + lane15;
                const int row0 = m0 + wmr + fi*16 + quad*4;
                const int b = row0 >> 11, ll = row0 & 2047;
                const int bh = (b << 4) + (col >> 7);
                const float bias = vb[col];
                f16x4 ph;
#pragma unroll
                for (int r = 0; r < 4; r++)
                    ph[r] = (f16)(acc[fi][j][r] * scale + bias);
                *(f16x4*)&Vt[((size_t)(bh*128 + (col & 127)))*(size_t)L_ + ll] = ph;
            }
    } else {
        f16* Cout = z==0 ? C0 : C1;
#pragma unroll
        for (int fi = 0; fi < 8; fi++)
#pragma unroll
            for (int j = 0; j < 4; j++) {
                const int col = n0 + wnc + j*16 + lane15;
#pragma unroll
                for (int r = 0; r < 4; r++) {
                    const int row = m0 + wmr + fi*16 + quad*4 + r;
                    Cout[(size_t)row*N + col] = (f16)(acc[fi][j][r] * scale);
                }
            }
    }
}

// ---------------------------------------------------------------------------
// Final projection GEMM, f32 out: 256x128 tile / BK=32 / 4 waves / TRIPLE-
// buffered LDS (72 KiB).  Grid 16x16 = 256 blocks = EXACTLY 1 block/CU,
// single dispatch round (R4 measured ~812 cyc/K-step under 2-way CU sharing;
// solo is <= that -> wall ~64*850 cyc ~ 23 us vs ~50 us for the 128^2
// 2-phase version).  Same verified swizzle/frag layout as gemm3b (R4,
// refcheck-passed).
// ---------------------------------------------------------------------------
__global__ __launch_bounds__(256, 2) void gemm3b_o(
    const f16* __restrict__ A, const f16* __restrict__ Bw,
    float* __restrict__ Cout, int K, float scale)
{
    __shared__ f16 lds[36864];   // 72 KiB: 3 x (A[256][32] + B[128][32])

    // T1 swizzle over 256 tiles (16 rows x 16 cols); XCD k gets 32
    // consecutive tiles = 2 full row-panels.
    const u32 lid = blockIdx.x + blockIdx.y * 16;      // 0..255
    const u32 swz = (lid & 7) * 32 + (lid >> 3);
    const int m0 = (int)(swz >> 4) * 256;
    const int n0 = (int)(swz & 15) * 128;

    const int t = threadIdx.x;                // 0..255
    const int w = t >> 6, l = t & 63;
    const int lane15 = l & 15, quad = l >> 4;
    const int wmr = (w >> 1) * 128;           // wave row block (0/128)
    const int wnc = (w & 1) * 64;             // wave col block (0/64)
    const int xslot = (quad ^ ((lane15 >> 1) & 3)) * 8;

    const int srow = t >> 2;
    const int cs   = (((t & 3) ^ ((t >> 3) & 3))) * 8;
    const f16* Ag = A  + (size_t)(m0 + srow) * K + cs;
    const f16* Bg = Bw + (size_t)(n0 + srow) * K + cs;
    f16* const ldst = lds + t * 8;
    const size_t K64 = (size_t)64 * K;

#define STAGE(T, SB) {                                        \
    f16* d_ = ldst + (SB) * 12288;                            \
    const f16* a_ = Ag + (T) * 32;                            \
    gload_lds16(a_,           d_);                            \
    gload_lds16(a_ +   K64,   d_ + 2048);                     \
    gload_lds16(a_ + 2*K64,   d_ + 4096);                     \
    gload_lds16(a_ + 3*K64,   d_ + 6144);                     \
    const f16* b_ = Bg + (T) * 32;                            \
    gload_lds16(b_,           d_ + 8192);                     \
    gload_lds16(b_ +   K64,   d_ + 10240); }

    f32x4 acc[8][4] = {};

    STAGE(0, 0); STAGE(1, 1);
    asm volatile("s_waitcnt vmcnt(6)" ::: "memory");
    __builtin_amdgcn_s_barrier();

    int cur = 0;
    const int NT = K >> 5;   // 64
    for (int kt = 0; kt < NT; ++kt) {
        int sb = cur + 2; if (sb >= 3) sb -= 3;
        const bool pf = (kt + 2 < NT);
        if (pf) STAGE(kt + 2, sb);

        const f16* Ab = lds + cur * 12288;
        const f16* Bb = Ab + 8192;
        f16x8 af[8], bf[4];
#pragma unroll
        for (int fi = 0; fi < 8; fi++) {
            const int r = wmr + fi*16 + lane15;
            af[fi] = *(const f16x8*)&Ab[r*32 + xslot];
        }
#pragma unroll
        for (int j = 0; j < 4; j++) {
            const int r = wnc + j*16 + lane15;
            bf[j] = *(const f16x8*)&Bb[r*32 + xslot];
        }
        __builtin_amdgcn_s_setprio(1);
#pragma unroll
        for (int fi = 0; fi < 8; fi++)
#pragma unroll
            for (int j = 0; j < 4; j++)
                acc[fi][j] = __builtin_amdgcn_mfma_f32_16x16x32_f16(
                    af[fi], bf[j], acc[fi][j], 0, 0, 0);
        __builtin_amdgcn_s_setprio(0);

        if (pf) { asm volatile("s_waitcnt vmcnt(6)" ::: "memory"); }
        else    { asm volatile("s_waitcnt vmcnt(0)" ::: "memory"); }
        __builtin_amdgcn_s_barrier();
        cur = cur + 1; if (cur == 3) cur = 0;
    }
#undef STAGE

#pragma unroll
    for (int fi = 0; fi < 8; fi++)
#pragma unroll
        for (int j = 0; j < 4; j++) {
            const int col = n0 + wnc + j*16 + lane15;
#pragma unroll
            for (int r = 0; r < 4; r++) {
                const int row = m0 + wmr + fi*16 + quad*4 + r;
                Cout[(size_t)row*HID_ + col] = acc[fi][j][r] * scale;
            }
        }
}

// ---------------------------------------------------------------------------
// mask int32 -> bitset. grid 1024 x 256
// ---------------------------------------------------------------------------
__global__ __launch_bounds__(256) void mask_pack(const int* __restrict__ m,
                                                 u32* __restrict__ bits)
{
    const int g = blockIdx.x*256 + threadIdx.x;
    const int* p = m + (size_t)g*32;
    u32 w = 0;
#pragma unroll
    for (int j = 0; j < 8; j++) {
        int4 v = *(const int4*)&p[j*4];
        w |= (v.x!=0 ? 1u:0u) << (j*4+0);
        w |= (v.y!=0 ? 1u:0u) << (j*4+1);
        w |= (v.z!=0 ? 1u:0u) << (j*4+2);
        w |= (v.w!=0 ? 1u:0u) << (j*4+3);
    }
    bits[g] = w;
}

// ---------------------------------------------------------------------------
// RMSNorm(full 2048) + neox RoPE + k_bias, in-place on f16 Q,K. 1 block/row.
// RoPE table FUSED: threads t<64 compute the row's fp64 sincos into LDS
// (ready by the existing reduction barrier) — removes the rope_table kernel
// and its 2x1 MB global round-trip.
// ---------------------------------------------------------------------------
__global__ __launch_bounds__(256) void norm_rope(
    f16* __restrict__ Q, f16* __restrict__ K,
    const float* __restrict__ qw, const float* __restrict__ kw,
    const float* __restrict__ kb, const int* __restrict__ pos)
{
    const int r = blockIdx.x;
    const int t = threadIdx.x;
    const size_t base = (size_t)r * HID_;

    __shared__ float cs[64], sn[64];
    if (t < 64) {
        double inv = exp2(-(double)t * (13.287712379549449 / 64.0)); // 10000^(-t/64)
        double a = (double)pos[r] * inv;
        double sd, cd;
        sincos(a, &sd, &cd);
        cs[t] = (float)cd;
        sn[t] = (float)sd;
    }

    const int p0 = t * 4;
    const int hh = p0 >> 6;
    const int i0 = p0 & 63;
    const int c1 = hh * 128 + i0;
    f16x4 q1h = *(f16x4*)&Q[base + c1];
    f16x4 q2h = *(f16x4*)&Q[base + c1 + 64];
    f16x4 k1h = *(f16x4*)&K[base + c1];
    f16x4 k2h = *(f16x4*)&K[base + c1 + 64];
    float q1[4], q2[4], k1[4], k2[4];
#pragma unroll
    for (int j = 0; j < 4; j++) {
        q1[j]=(float)q1h[j]; q2[j]=(float)q2h[j];
        k1[j]=(float)k1h[j]; k2[j]=(float)k2h[j];
    }

    float ssq = 0.f, ssk = 0.f;
#pragma unroll
    for (int j = 0; j < 4; j++) {
        ssq += q1[j]*q1[j] + q2[j]*q2[j];
        ssk += k1[j]*k1[j] + k2[j]*k2[j];
    }
#pragma unroll
    for (int off = 1; off < 64; off <<= 1) {
        ssq += __shfl_xor(ssq, off);
        ssk += __shfl_xor(ssk, off);
    }
    __shared__ float rq[4], rk[4];
    const int wave = t >> 6, lane = t & 63;
    if (lane == 0) { rq[wave] = ssq; rk[wave] = ssk; }
    __syncthreads();                     // also publishes cs/sn
    ssq = rq[0] + rq[1] + rq[2] + rq[3];
    ssk = rk[0] + rk[1] + rk[2] + rk[3];
    const float rsq = rsqrtf(ssq * (1.f / HID_) + 1e-6f);
    const float rsk = rsqrtf(ssk * (1.f / HID_) + 1e-6f);

    float4 cos4 = *(const float4*)&cs[i0];
    float4 sin4 = *(const float4*)&sn[i0];
    float cc[4] = {cos4.x, cos4.y, cos4.z, cos4.w};
    float ss[4] = {sin4.x, sin4.y, sin4.z, sin4.w};

    f16x4 oq1, oq2, ok1, ok2;
#pragma unroll
    for (int j = 0; j < 4; j++) {
        const float c = cc[j], s = ss[j];
        const float wq1 = 1.f + qw[c1 + j], wq2 = 1.f + qw[c1 + 64 + j];
        const float wk1 = 1.f + kw[c1 + j], wk2 = 1.f + kw[c1 + 64 + j];
        float qa = q1[j] * rsq * wq1, qb = q2[j] * rsq * wq2;
        oq1[j] = (f16)(qa * c - qb * s);
        oq2[j] = (f16)(qb * c + qa * s);
        float ka = k1[j] * rsk * wk1, kbv = k2[j] * rsk * wk2;
        ok1[j] = (f16)(ka * c - kbv * s + kb[c1 + j]);
        ok2[j] = (f16)(kbv * c + ka * s + kb[c1 + 64 + j]);
    }
    *(f16x4*)&Q[base + c1]      = oq1;
    *(f16x4*)&Q[base + c1 + 64] = oq2;
    *(f16x4*)&K[base + c1]      = ok1;
    *(f16x4*)&K[base + c1 + 64] = ok2;
}

// ---------------------------------------------------------------------------
// MFMA flash attention, double-buffered global_load_lds pipeline. (unchanged)
// ---------------------------------------------------------------------------
__global__ __launch_bounds__(256, 2) void flash16(
    const f16* __restrict__ Qh, const f16* __restrict__ Kh,
    const f16* __restrict__ Vtg, const u32* __restrict__ bits,
    f16* __restrict__ AOh)
{
    __shared__ f16 lds[40960];   // 80 KiB

    const int t = threadIdx.x;
    const int w = t >> 6, l = t & 63;
    const int lane15 = l & 15, quad = l >> 4;
    const int bh = blockIdx.y;
    const int b = bh >> 4, h = bh & 15;
    const int q0 = blockIdx.x * 128;

    const size_t qkbase = ((size_t)(b*L_))*HID_ + h*128;   // Q/K row base
    const size_t vbase  = ((size_t)(bh*128))*L_;           // Vt row base

    // ---- stage Q tile into lds[0..16384) as swizzled [128][128]
#pragma unroll
    for (int i = 0; i < 8; i++) {
        int f = t + i*256;                 // 16B slot 0..2047
        int row = f >> 4, c4 = f & 15;
        int c = c4 ^ (row & 15);
        *(uint4*)&lds[row*128 + c4*8] =
            *(const uint4*)&Qh[qkbase + (size_t)(q0 + row)*HID_ + c*8];
    }
    __syncthreads();
    f16x8 qf[2][4];
#pragma unroll
    for (int qt = 0; qt < 2; qt++)
#pragma unroll
        for (int dc = 0; dc < 4; dc++)
            qf[qt][dc] = *(const f16x8*)&lds[(w*32 + qt*16 + lane15)*128
                                             + (((dc*4 + quad) ^ lane15) * 8)];
    __syncthreads();   // Q area about to be overwritten by K prefetch

    // ---- prefetch tile 0 into buffer 0
    {
        f16* Kb = lds;            f16* Vb = lds + 16384;
#pragma unroll
        for (int it = 0; it < 4; it++) {
            int j = w*256 + it*64 + l;      // 0..1023
            int krow = j >> 4, kc = (j & 15) ^ (krow & 15);
            gload_lds16(Kh + qkbase + (size_t)krow*HID_ + kc*8, Kb + j*8);
            int vrow = j >> 3, vc = (j & 7) ^ (vrow & 7);
            gload_lds16(Vtg + vbase + (size_t)vrow*L_ + vc*8, Vb + j*8);
        }
    }

    f32x4 oacc[2][8] = {};
    float lsum[2] = {0.f, 0.f};

    for (int kt = 0; kt < 32; kt++) {
        const int k0 = kt * 64;
        __syncthreads();   // drains vmcnt(0): tile kt DMA visible

        if (kt + 1 < 32) {
            const int kn = k0 + 64;
            f16* Kb = lds + ((kt+1) & 1)*8192;
            f16* Vb = lds + 16384 + ((kt+1) & 1)*8192;
#pragma unroll
            for (int it = 0; it < 4; it++) {
                int j = w*256 + it*64 + l;
                int krow = j >> 4, kc = (j & 15) ^ (krow & 15);
                gload_lds16(Kh + qkbase + (size_t)(kn + krow)*HID_ + kc*8, Kb + j*8);
                int vrow = j >> 3, vc = (j & 7) ^ (vrow & 7);
                gload_lds16(Vtg + vbase + (size_t)vrow*L_ + kn + vc*8, Vb + j*8);
            }
        }
        const f16* Kb = lds + (kt & 1)*8192;
        const f16* Vb = lds + 16384 + (kt & 1)*8192;
        f16* Ps = lds + 32768;

        u32 mw[2][2];
#pragma unroll
        for (int qt = 0; qt < 2; qt++) {
            int qrow = q0 + w*32 + qt*16 + lane15;
            const u32* bp = bits + (((size_t)(b*L_ + qrow)) << 6) + (k0 >> 5);
            mw[qt][0] = bp[0];
            mw[qt][1] = bp[1];
        }

        // ---- S^T = K * Q^T
        f32x4 st[2][4];
#pragma unroll
        for (int kt2 = 0; kt2 < 4; kt2++) {
            f16x8 kf[4];
#pragma unroll
            for (int dc = 0; dc < 4; dc++)
                kf[dc] = *(const f16x8*)&Kb[(kt2*16 + lane15)*128
                                            + (((dc*4 + quad) ^ lane15) * 8)];
#pragma unroll
            for (int qt = 0; qt < 2; qt++) {
                f32x4 a = {0.f, 0.f, 0.f, 0.f};
#pragma unroll
                for (int dc = 0; dc < 4; dc++)
                    a = __builtin_amdgcn_mfma_f32_16x16x32_f16(kf[dc], qf[qt][dc], a, 0, 0, 0);
                st[qt][kt2] = a;
            }
        }

        // ---- poly soft-cap + mask + fixed-max exp, P -> LDS
#pragma unroll
        for (int qt = 0; qt < 2; qt++) {
            const int prow = (w*32 + qt*16 + lane15) * 64;
            float ls = 0.f;
#pragma unroll
            for (int kt2 = 0; kt2 < 4; kt2++) {
                const u32 w_ = mw[qt][kt2 >> 1];
                f16x4 ph;
#pragma unroll
                for (int r = 0; r < 4; r++) {
                    float x = st[qt][kt2][r];
                    float y = x * x;
                    float p5 = fmaf(CAP_C2, y, CAP_C1);
                    float wv = fmaf(p5, y, CAP_C0);
                    float e = fmaf(x, wv, -FIXED_M2);
                    int kk = kt2*16 + quad*4 + r;
                    e = ((w_ >> (kk & 31)) & 1u) ? e : -150.f;
                    float pv = fexp2(e);
                    ls += pv;
                    ph[r] = (f16)pv;
                }
                const int c16s = (kt2*2 + (quad >> 1)) ^ (lane15 & 7);
                *(f16x4*)&Ps[prow + c16s*8 + (quad & 1)*4] = ph;
            }
            lsum[qt] += ls;
        }
        // no barrier: PV reads only this wave's own Ps rows (in-order DS)

        // ---- O += P * V
        f16x8 pf[2][2];
#pragma unroll
        for (int qt = 0; qt < 2; qt++)
#pragma unroll
            for (int c = 0; c < 2; c++)
                pf[qt][c] = *(const f16x8*)&Ps[(w*32 + qt*16 + lane15)*64
                                               + (((c*4 + quad) ^ (lane15 & 7)) * 8)];
#pragma unroll
        for (int dt = 0; dt < 8; dt++) {
            f16x8 vf[2];
#pragma unroll
            for (int c = 0; c < 2; c++)
                vf[c] = *(const f16x8*)&Vb[(dt*16 + lane15)*64
                                           + (((c*4 + quad) ^ (lane15 & 7)) * 8)];
#pragma unroll
            for (int qt = 0; qt < 2; qt++)
#pragma unroll
                for (int c = 0; c < 2; c++)
                    oacc[qt][dt] = __builtin_amdgcn_mfma_f32_16x16x32_f16(pf[qt][c], vf[c], oacc[qt][dt], 0, 0, 0);
        }
    }

    // ---- epilogue: l-reduce over quads, divide, store via LDS repack
#pragma unroll
    for (int qt = 0; qt < 2; qt++) {
        lsum[qt] += __shfl_xor(lsum[qt], 16);
        lsum[qt] += __shfl_xor(lsum[qt], 32);
    }
    __syncthreads();   // all LDS reads done; reuse lds[0..17408) as Ot [128][136]
    f16* Ot = lds;
#pragma unroll
    for (int qt = 0; qt < 2; qt++) {
#pragma unroll
        for (int r = 0; r < 4; r++) {
            float inv = frcp(__shfl(lsum[qt], quad*4 + r));
            const int row = w*32 + qt*16 + quad*4 + r;
#pragma unroll
            for (int dt = 0; dt < 8; dt++)
                Ot[row*136 + dt*16 + lane15] = (f16)(oacc[qt][dt][r] * inv);
        }
    }
    __syncthreads();
#pragma unroll
    for (int i = 0; i < 8; i++) {
        int f = t + i*256;
        int row = f >> 4, ch = f & 15;
        *(uint4*)&AOh[qkbase + (size_t)(q0 + row)*HID_ + ch*8] =
            *(const uint4*)&Ot[row*136 + ch*8];
    }
}

// ---------------------------------------------------------------------------
extern "C" void kernel_launch(void* const* d_in, const int* in_sizes, int n_in,
                              void* d_out, int out_size, void* d_ws, size_t ws_size,
                              hipStream_t stream)
{
    const float* hs  = (const float*)d_in[0];
    const float* Wq  = (const float*)d_in[1];
    const float* Wk  = (const float*)d_in[2];
    const float* Wv  = (const float*)d_in[3];
    const float* Wo  = (const float*)d_in[4];
    const float* qw  = (const float*)d_in[5];
    const float* kw  = (const float*)d_in[6];
    const float* kb  = (const float*)d_in[7];
    const float* vb  = (const float*)d_in[8];
    const int*   pos = (const int*)d_in[9];
    const int*   mask = (const int*)d_in[10];
    float* out = (float*)d_out;

    char* W = (char*)d_ws;
    f16* hs16 = (f16*)(W);                     // 16.8 MB; later AOh
    f16* w16o = (f16*)(W + 16777216);          // 8.4 MB
    f16* w16q = (f16*)(W + 25165824);          // 8.4 MB
    f16* w16k = (f16*)(W + 33554432);          // 8.4 MB
    f16* w16v = (f16*)(W + 41943040);          // 8.4 MB; later bits
    f16* Q16  = (f16*)(W + 50331648);          // 16.8 MB
    f16* K16  = (f16*)(W + 67108864);          // 16.8 MB
    f16* Vtg  = (f16*)(W + 83886080);          // 16.8 MB (V written transposed)
    u32*  bits = (u32*) (W + 41943040);
    f16* AOh = hs16;

    const int M = B_ * L_;          // 4096
    const int nHS = M * HID_;       // 8388608
    const int nW  = HID_ * HID_;    // 4194304

    cvt5<<<dim3(4096, 5), 256, 0, stream>>>(hs, Wq, Wk, Wv, Wo,
                                            hs16, w16q, w16k, w16v, w16o, nHS, nW);

    gemm8p_qkv<<<dim3(HID_/256, M/256, 3), 512, 0, stream>>>(
        hs16, w16q, w16k, w16v, Q16, K16, Vtg, vb, M, HID_, HID_, FAN_IN);

    mask_pack<<<1024, 256, 0, stream>>>(mask, bits);

    norm_rope<<<M, 256, 0, stream>>>(Q16, K16, qw, kw, kb, pos);

    flash16<<<dim3(16, 32), 256, 0, stream>>>(Q16, K16, Vtg, bits, AOh);

    gemm3b_o<<<dim3(16, 16), 256, 0, stream>>>(
        AOh, w16o, out, HID_, FAN_IN);
}

// Round 6
// 444.366 us; speedup vs baseline: 1.0267x; 1.0209x over previous
//
#include <hip/hip_runtime.h>
#include <math.h>

#define B_  2
#define L_  2048
#define HID_ 2048
#define H_  16
#define D_  128
#define FAN_IN 0.02209708691207961f   // 1/sqrt(2048)
#define SM_SCALE 0.08838834764831845f // 1/sqrt(128)
#define LOG2E 1.4426950408889634

typedef _Float16 f16;
typedef unsigned int u32;
typedef __attribute__((ext_vector_type(4))) _Float16 f16x4;
typedef __attribute__((ext_vector_type(8))) _Float16 f16x8;
typedef __attribute__((ext_vector_type(4))) float f32x4;

// soft-cap poly in log2 domain: f(x) = 30*tanh(x*SM_SCALE/30)*LOG2E
#define CAP_C0 0.12751738960681625f
#define CAP_C1 (-3.690028637e-7f)
#define CAP_C2 (1.28121e-12f)
#define FIXED_M2 8.0f    // fixed softmax max in log2 units

__device__ __forceinline__ float fexp2(float x) {
#if __has_builtin(__builtin_amdgcn_exp2f)
    return __builtin_amdgcn_exp2f(x);
#else
    return exp2f(x);
#endif
}
__device__ __forceinline__ float frcp(float x) {
#if __has_builtin(__builtin_amdgcn_rcpf)
    return __builtin_amdgcn_rcpf(x);
#else
    return 1.0f / x;
#endif
}
__device__ __forceinline__ void gload_lds16(const void* g, void* l) {
#if __has_builtin(__builtin_amdgcn_global_load_lds)
    __builtin_amdgcn_global_load_lds(
        (const __attribute__((address_space(1))) u32*)g,
        (__attribute__((address_space(3))) u32*)l, 16, 0, 0);
#else
    *(uint4*)l = *(const uint4*)g;
#endif
}

// ---------------------------------------------------------------------------
// fp32 -> f16 conversion for hs + 4 weight matrices.  Flat exact grid:
// blocks 0..4095 -> hs (8.4M elems), then 4 x 2048 blocks -> each weight
// (4.2M elems).  No dead blocks, no bounds check (R5 launched 2x blocks for
// the weight segments; half idled on the bounds test).
// ---------------------------------------------------------------------------
__global__ __launch_bounds__(256) void cvt5(
    const float* __restrict__ s0, const float* __restrict__ s1,
    const float* __restrict__ s2, const float* __restrict__ s3,
    const float* __restrict__ s4,
    f16* __restrict__ d0, f16* __restrict__ d1, f16* __restrict__ d2,
    f16* __restrict__ d3, f16* __restrict__ d4)
{
    const int bid = blockIdx.x;
    int seg, off;
    if (bid < 4096) { seg = 0; off = bid; }
    else { const int r = bid - 4096; seg = 1 + (r >> 11); off = r & 2047; }
    const float* s = seg==0?s0:seg==1?s1:seg==2?s2:seg==3?s3:s4;
    f16* d = seg==0?d0:seg==1?d1:seg==2?d2:seg==3?d3:d4;
    const int i = (off*256 + threadIdx.x)*8;
    float4 a = *(const float4*)&s[i];
    float4 b = *(const float4*)&s[i+4];
    f16x8 o;
    o[0]=(f16)a.x; o[1]=(f16)a.y; o[2]=(f16)a.z; o[3]=(f16)a.w;
    o[4]=(f16)b.x; o[5]=(f16)b.y; o[6]=(f16)b.z; o[7]=(f16)b.w;
    *(f16x8*)&d[i] = o;
}

// ---------------------------------------------------------------------------
// Fused QKV GEMM — R2 kernel (best measured: 126.5-127.4 us).  FROZEN.
// 256x256 tile / BK=64 / 8 waves, 8-phase iteration, one region staged per
// phase, uniform vmcnt(10) before odd phases.
// ---------------------------------------------------------------------------
__global__ __launch_bounds__(512, 2) void gemm8p_qkv(
    const f16* __restrict__ A,
    const f16* __restrict__ Bq, const f16* __restrict__ Bk,
    const f16* __restrict__ Bv,
    f16* __restrict__ C0, f16* __restrict__ C1,
    f16* __restrict__ Vt, const float* __restrict__ vb,
    int M, int N, int K, float scale)
{
    __shared__ f16 lds[65536];   // 128 KiB

    const u32 lid = blockIdx.x + (blockIdx.y << 3) + (blockIdx.z << 7);
    const u32 swz = (lid & 7) * 48 + (lid >> 3);
    const int n0 = (swz & 7) * 256;
    const int m0 = ((swz >> 3) & 15) * 256;
    const int z  = swz >> 7;
    const f16* Bw = z==0 ? Bq : z==1 ? Bk : Bv;

    const int t = threadIdx.x;            // 0..511
    const int w = t >> 6, l = t & 63;
    const int lane15 = l & 15, quad = l >> 4;
    const int wmr = (w >> 2) * 128;       // wave row block (0/128)
    const int wnc = (w & 3) * 64;         // wave col block
    const int xslot = (quad ^ ((lane15 >> 1) & 3)) * 8;   // swizzled frag slot

    const int srow = t >> 2;
    const int sc   = t & 3;
    const int cs0 = (sc ^ ((srow >> 1) & 3)) * 8;
    const f16* Ag0 = A  + (size_t)(m0 + srow) * K + cs0;
    const f16* Ag1 = A  + (size_t)(m0 + 128 + srow) * K + cs0;
    const f16* Bg0 = Bw + (size_t)(n0 + srow) * K + cs0;
    const f16* Bg1 = Bw + (size_t)(n0 + 128 + srow) * K + cs0;
    f16* const ldst = lds + t * 8;

#define STG_A(BUF, S, KOFF) {                                             \
    gload_lds16(Ag0 + (KOFF), ldst + (BUF) + (S)*16384);                  \
    gload_lds16(Ag1 + (KOFF), ldst + (BUF) + (S)*16384 + 4096); }
#define STG_B(BUF, S, KOFF) {                                             \
    gload_lds16(Bg0 + (KOFF), ldst + (BUF) + (S)*16384 + 8192);           \
    gload_lds16(Bg1 + (KOFF), ldst + (BUF) + (S)*16384 + 12288); }
#define WV(N) asm volatile("s_waitcnt vmcnt(" #N ")" ::: "memory")
#define BAR() __builtin_amdgcn_s_barrier()

    f32x4 acc[8][4] = {};
    f16x8 bfr[4];

#define PHASE(BUFO, S, H, ...)                                            \
    {                                                                     \
        const f16* Ab_ = lds + (BUFO) + (S)*16384;                        \
        f16x8 af[4];                                                      \
        _Pragma("unroll")                                                 \
        for (int i = 0; i < 4; i++) {                                     \
            const int r = wmr + (H)*64 + i*16 + lane15;                   \
            af[i] = *(const f16x8*)&Ab_[r*32 + xslot];                    \
        }                                                                 \
        if ((H) == 0) {                                                   \
            const f16* Bb_ = Ab_ + 8192;                                  \
            _Pragma("unroll")                                             \
            for (int j = 0; j < 4; j++) {                                 \
                const int r = wnc + j*16 + lane15;                        \
                bfr[j] = *(const f16x8*)&Bb_[r*32 + xslot];               \
            }                                                             \
        }                                                                 \
        __VA_ARGS__;                                                      \
        __builtin_amdgcn_s_barrier();                                     \
        __builtin_amdgcn_s_setprio(1);                                    \
        _Pragma("unroll")                                                 \
        for (int i = 0; i < 4; i++)                                       \
            _Pragma("unroll")                                             \
            for (int j = 0; j < 4; j++)                                   \
                acc[(H)*4+i][j] = __builtin_amdgcn_mfma_f32_16x16x32_f16( \
                    af[i], bfr[j], acc[(H)*4+i][j], 0, 0, 0);             \
        __builtin_amdgcn_s_setprio(0);                                    \
    }

    // ---- prologue: tile 0 (4 regions) + tile 1 (B0,A0,B1) = 14 loads
    STG_B(0, 0, 0);  STG_A(0, 0, 0);  STG_B(0, 1, 32);  STG_A(0, 1, 32);
    STG_B(32768, 0, 64);  STG_A(32768, 0, 64);  STG_B(32768, 1, 96);
    WV(10); BAR();

    const int NIT = (K >> 7) - 1;   // 15
    for (int it = 0; it < NIT; ++it) {
        const int kB = it * 128;
        const int k1A = kB + 96;          // tile 2it+1, ksub1
        const int kE  = kB + 128;         // tile 2it+2
        const int kO  = kB + 192;         // tile 2it+3

        PHASE(0,     0, 0, STG_A(32768, 1, k1A))        // P1
        BAR();
        PHASE(0,     0, 1, STG_B(0,     0, kE))         // P2
        WV(10); BAR();
        PHASE(0,     1, 0, STG_A(0,     0, kE))         // P3
        BAR();
        PHASE(0,     1, 1, STG_B(0,     1, kE + 32))    // P4
        WV(10); BAR();
        PHASE(32768, 0, 0, STG_A(0,     1, kE + 32))    // P5
        BAR();
        PHASE(32768, 0, 1, STG_B(32768, 0, kO))         // P6
        WV(10); BAR();
        PHASE(32768, 1, 0, STG_A(32768, 0, kO))         // P7
        BAR();
        PHASE(32768, 1, 1, STG_B(32768, 1, kO + 32))    // P8
        WV(10); BAR();
    }

    // ---- peeled last iter (K-tiles 30,31)
    {
        const int k1A = NIT * 128 + 96;                 // 2016
        PHASE(0,     0, 0, STG_A(32768, 1, k1A))        // P1
        BAR();
        PHASE(0,     0, 1, )                            // P2
        WV(8); BAR();
        PHASE(0,     1, 0, )                            // P3
        BAR();
        PHASE(0,     1, 1, )                            // P4
        WV(4); BAR();
        PHASE(32768, 0, 0, )                            // P5
        BAR();
        PHASE(32768, 0, 1, )                            // P6
        WV(0); BAR();
        PHASE(32768, 1, 0, )                            // P7
        BAR();
        PHASE(32768, 1, 1, )                            // P8
    }

#undef PHASE
#undef STG_A
#undef STG_B
#undef WV
#undef BAR

    if (z == 2) {
#pragma unroll
        for (int fi = 0; fi < 8; fi++)
#pragma unroll
            for (int j = 0; j < 4; j++) {
                const int col = n0 + wnc + j*16 + lane15;
                const int row0 = m0 + wmr + fi*16 + quad*4;
                const int b = row0 >> 11, ll = row0 & 2047;
                const int bh = (b << 4) + (col >> 7);
                const float bias = vb[col];
                f16x4 ph;
#pragma unroll
                for (int r = 0; r < 4; r++)
                    ph[r] = (f16)(acc[fi][j][r] * scale + bias);
                *(f16x4*)&Vt[((size_t)(bh*128 + (col & 127)))*(size_t)L_ + ll] = ph;
            }
    } else {
        f16* Cout = z==0 ? C0 : C1;
#pragma unroll
        for (int fi = 0; fi < 8; fi++)
#pragma unroll
            for (int j = 0; j < 4; j++) {
                const int col = n0 + wnc + j*16 + lane15;
#pragma unroll
                for (int r = 0; r < 4; r++) {
                    const int row = m0 + wmr + fi*16 + quad*4 + r;
                    Cout[(size_t)row*N + col] = (f16)(acc[fi][j][r] * scale);
                }
            }
    }
}

// ---------------------------------------------------------------------------
// Final projection GEMM, f32 out: 256x128 tile / BK=32 / 4 waves / triple-
// buffered LDS, grid 16x16 (1 block/CU, 1 round).  (unchanged from R5)
// ---------------------------------------------------------------------------
__global__ __launch_bounds__(256, 2) void gemm3b_o(
    const f16* __restrict__ A, const f16* __restrict__ Bw,
    float* __restrict__ Cout, int K, float scale)
{
    __shared__ f16 lds[36864];   // 72 KiB: 3 x (A[256][32] + B[128][32])

    const u32 lid = blockIdx.x + blockIdx.y * 16;      // 0..255
    const u32 swz = (lid & 7) * 32 + (lid >> 3);
    const int m0 = (int)(swz >> 4) * 256;
    const int n0 = (int)(swz & 15) * 128;

    const int t = threadIdx.x;                // 0..255
    const int w = t >> 6, l = t & 63;
    const int lane15 = l & 15, quad = l >> 4;
    const int wmr = (w >> 1) * 128;           // wave row block (0/128)
    const int wnc = (w & 1) * 64;             // wave col block (0/64)
    const int xslot = (quad ^ ((lane15 >> 1) & 3)) * 8;

    const int srow = t >> 2;
    const int cs   = (((t & 3) ^ ((t >> 3) & 3))) * 8;
    const f16* Ag = A  + (size_t)(m0 + srow) * K + cs;
    const f16* Bg = Bw + (size_t)(n0 + srow) * K + cs;
    f16* const ldst = lds + t * 8;
    const size_t K64 = (size_t)64 * K;

#define STAGE(T, SB) {                                        \
    f16* d_ = ldst + (SB) * 12288;                            \
    const f16* a_ = Ag + (T) * 32;                            \
    gload_lds16(a_,           d_);                            \
    gload_lds16(a_ +   K64,   d_ + 2048);                     \
    gload_lds16(a_ + 2*K64,   d_ + 4096);                     \
    gload_lds16(a_ + 3*K64,   d_ + 6144);                     \
    const f16* b_ = Bg + (T) * 32;                            \
    gload_lds16(b_,           d_ + 8192);                     \
    gload_lds16(b_ +   K64,   d_ + 10240); }

    f32x4 acc[8][4] = {};

    STAGE(0, 0); STAGE(1, 1);
    asm volatile("s_waitcnt vmcnt(6)" ::: "memory");
    __builtin_amdgcn_s_barrier();

    int cur = 0;
    const int NT = K >> 5;   // 64
    for (int kt = 0; kt < NT; ++kt) {
        int sb = cur + 2; if (sb >= 3) sb -= 3;
        const bool pf = (kt + 2 < NT);
        if (pf) STAGE(kt + 2, sb);

        const f16* Ab = lds + cur * 12288;
        const f16* Bb = Ab + 8192;
        f16x8 af[8], bf[4];
#pragma unroll
        for (int fi = 0; fi < 8; fi++) {
            const int r = wmr + fi*16 + lane15;
            af[fi] = *(const f16x8*)&Ab[r*32 + xslot];
        }
#pragma unroll
        for (int j = 0; j < 4; j++) {
            const int r = wnc + j*16 + lane15;
            bf[j] = *(const f16x8*)&Bb[r*32 + xslot];
        }
        __builtin_amdgcn_s_setprio(1);
#pragma unroll
        for (int fi = 0; fi < 8; fi++)
#pragma unroll
            for (int j = 0; j < 4; j++)
                acc[fi][j] = __builtin_amdgcn_mfma_f32_16x16x32_f16(
                    af[fi], bf[j], acc[fi][j], 0, 0, 0);
        __builtin_amdgcn_s_setprio(0);

        if (pf) { asm volatile("s_waitcnt vmcnt(6)" ::: "memory"); }
        else    { asm volatile("s_waitcnt vmcnt(0)" ::: "memory"); }
        __builtin_amdgcn_s_barrier();
        cur = cur + 1; if (cur == 3) cur = 0;
    }
#undef STAGE

#pragma unroll
    for (int fi = 0; fi < 8; fi++)
#pragma unroll
        for (int j = 0; j < 4; j++) {
            const int col = n0 + wnc + j*16 + lane15;
#pragma unroll
            for (int r = 0; r < 4; r++) {
                const int row = m0 + wmr + fi*16 + quad*4 + r;
                Cout[(size_t)row*HID_ + col] = acc[fi][j][r] * scale;
            }
        }
}

// ---------------------------------------------------------------------------
// mask int32 -> bitset. grid 1024 x 256
// ---------------------------------------------------------------------------
__global__ __launch_bounds__(256) void mask_pack(const int* __restrict__ m,
                                                 u32* __restrict__ bits)
{
    const int g = blockIdx.x*256 + threadIdx.x;
    const int* p = m + (size_t)g*32;
    u32 w = 0;
#pragma unroll
    for (int j = 0; j < 8; j++) {
        int4 v = *(const int4*)&p[j*4];
        w |= (v.x!=0 ? 1u:0u) << (j*4+0);
        w |= (v.y!=0 ? 1u:0u) << (j*4+1);
        w |= (v.z!=0 ? 1u:0u) << (j*4+2);
        w |= (v.w!=0 ? 1u:0u) << (j*4+3);
    }
    bits[g] = w;
}

// ---------------------------------------------------------------------------
// RMSNorm(full 2048) + neox RoPE + k_bias, in-place on f16 Q,K. 1 block/row.
// RoPE sincos fused in LDS (from R5).
// ---------------------------------------------------------------------------
__global__ __launch_bounds__(256) void norm_rope(
    f16* __restrict__ Q, f16* __restrict__ K,
    const float* __restrict__ qw, const float* __restrict__ kw,
    const float* __restrict__ kb, const int* __restrict__ pos)
{
    const int r = blockIdx.x;
    const int t = threadIdx.x;
    const size_t base = (size_t)r * HID_;

    __shared__ float cs[64], sn[64];
    if (t < 64) {
        double inv = exp2(-(double)t * (13.287712379549449 / 64.0)); // 10000^(-t/64)
        double a = (double)pos[r] * inv;
        double sd, cd;
        sincos(a, &sd, &cd);
        cs[t] = (float)cd;
        sn[t] = (float)sd;
    }

    const int p0 = t * 4;
    const int hh = p0 >> 6;
    const int i0 = p0 & 63;
    const int c1 = hh * 128 + i0;
    f16x4 q1h = *(f16x4*)&Q[base + c1];
    f16x4 q2h = *(f16x4*)&Q[base + c1 + 64];
    f16x4 k1h = *(f16x4*)&K[base + c1];
    f16x4 k2h = *(f16x4*)&K[base + c1 + 64];
    float q1[4], q2[4], k1[4], k2[4];
#pragma unroll
    for (int j = 0; j < 4; j++) {
        q1[j]=(float)q1h[j]; q2[j]=(float)q2h[j];
        k1[j]=(float)k1h[j]; k2[j]=(float)k2h[j];
    }

    float ssq = 0.f, ssk = 0.f;
#pragma unroll
    for (int j = 0; j < 4; j++) {
        ssq += q1[j]*q1[j] + q2[j]*q2[j];
        ssk += k1[j]*k1[j] + k2[j]*k2[j];
    }
#pragma unroll
    for (int off = 1; off < 64; off <<= 1) {
        ssq += __shfl_xor(ssq, off);
        ssk += __shfl_xor(ssk, off);
    }
    __shared__ float rq[4], rk[4];
    const int wave = t >> 6, lane = t & 63;
    if (lane == 0) { rq[wave] = ssq; rk[wave] = ssk; }
    __syncthreads();                     // also publishes cs/sn
    ssq = rq[0] + rq[1] + rq[2] + rq[3];
    ssk = rk[0] + rk[1] + rk[2] + rk[3];
    const float rsq = rsqrtf(ssq * (1.f / HID_) + 1e-6f);
    const float rsk = rsqrtf(ssk * (1.f / HID_) + 1e-6f);

    float4 cos4 = *(const float4*)&cs[i0];
    float4 sin4 = *(const float4*)&sn[i0];
    float cc[4] = {cos4.x, cos4.y, cos4.z, cos4.w};
    float ss[4] = {sin4.x, sin4.y, sin4.z, sin4.w};

    f16x4 oq1, oq2, ok1, ok2;
#pragma unroll
    for (int j = 0; j < 4; j++) {
        const float c = cc[j], s = ss[j];
        const float wq1 = 1.f + qw[c1 + j], wq2 = 1.f + qw[c1 + 64 + j];
        const float wk1 = 1.f + kw[c1 + j], wk2 = 1.f + kw[c1 + 64 + j];
        float qa = q1[j] * rsq * wq1, qb = q2[j] * rsq * wq2;
        oq1[j] = (f16)(qa * c - qb * s);
        oq2[j] = (f16)(qb * c + qa * s);
        float ka = k1[j] * rsk * wk1, kbv = k2[j] * rsk * wk2;
        ok1[j] = (f16)(ka * c - kbv * s + kb[c1 + j]);
        ok2[j] = (f16)(kbv * c + ka * s + kb[c1 + 64 + j]);
    }
    *(f16x4*)&Q[base + c1]      = oq1;
    *(f16x4*)&Q[base + c1 + 64] = oq2;
    *(f16x4*)&K[base + c1]      = ok1;
    *(f16x4*)&K[base + c1 + 64] = ok2;
}

// ---------------------------------------------------------------------------
// MFMA flash attention, double-buffered global_load_lds pipeline.
// R6 change: s_setprio(1) around both MFMA clusters (T5 — proven +4-7% on
// attn with independent blocks/CU at different phases, m191).  2 unsynced
// blocks/CU here = the regime where it pays.
// ---------------------------------------------------------------------------
__global__ __launch_bounds__(256, 2) void flash16(
    const f16* __restrict__ Qh, const f16* __restrict__ Kh,
    const f16* __restrict__ Vtg, const u32* __restrict__ bits,
    f16* __restrict__ AOh)
{
    __shared__ f16 lds[40960];   // 80 KiB

    const int t = threadIdx.x;
    const int w = t >> 6, l = t & 63;
    const int lane15 = l & 15, quad = l >> 4;
    const int bh = blockIdx.y;
    const int b = bh >> 4, h = bh & 15;
    const int q0 = blockIdx.x * 128;

    const size_t qkbase = ((size_t)(b*L_))*HID_ + h*128;   // Q/K row base
    const size_t vbase  = ((size_t)(bh*128))*L_;           // Vt row base

    // ---- stage Q tile into lds[0..16384) as swizzled [128][128]
#pragma unroll
    for (int i = 0; i < 8; i++) {
        int f = t + i*256;                 // 16B slot 0..2047
        int row = f >> 4, c4 = f & 15;
        int c = c4 ^ (row & 15);
        *(uint4*)&lds[row*128 + c4*8] =
            *(const uint4*)&Qh[qkbase + (size_t)(q0 + row)*HID_ + c*8];
    }
    __syncthreads();
    f16x8 qf[2][4];
#pragma unroll
    for (int qt = 0; qt < 2; qt++)
#pragma unroll
        for (int dc = 0; dc < 4; dc++)
            qf[qt][dc] = *(const f16x8*)&lds[(w*32 + qt*16 + lane15)*128
                                             + (((dc*4 + quad) ^ lane15) * 8)];
    __syncthreads();   // Q area about to be overwritten by K prefetch

    // ---- prefetch tile 0 into buffer 0
    {
        f16* Kb = lds;            f16* Vb = lds + 16384;
#pragma unroll
        for (int it = 0; it < 4; it++) {
            int j = w*256 + it*64 + l;      // 0..1023
            int krow = j >> 4, kc = (j & 15) ^ (krow & 15);
            gload_lds16(Kh + qkbase + (size_t)krow*HID_ + kc*8, Kb + j*8);
            int vrow = j >> 3, vc = (j & 7) ^ (vrow & 7);
            gload_lds16(Vtg + vbase + (size_t)vrow*L_ + vc*8, Vb + j*8);
        }
    }

    f32x4 oacc[2][8] = {};
    float lsum[2] = {0.f, 0.f};

    for (int kt = 0; kt < 32; kt++) {
        const int k0 = kt * 64;
        __syncthreads();   // drains vmcnt(0): tile kt DMA visible

        if (kt + 1 < 32) {
            const int kn = k0 + 64;
            f16* Kb = lds + ((kt+1) & 1)*8192;
            f16* Vb = lds + 16384 + ((kt+1) & 1)*8192;
#pragma unroll
            for (int it = 0; it < 4; it++) {
                int j = w*256 + it*64 + l;
                int krow = j >> 4, kc = (j & 15) ^ (krow & 15);
                gload_lds16(Kh + qkbase + (size_t)(kn + krow)*HID_ + kc*8, Kb + j*8);
                int vrow = j >> 3, vc = (j & 7) ^ (vrow & 7);
                gload_lds16(Vtg + vbase + (size_t)vrow*L_ + kn + vc*8, Vb + j*8);
            }
        }
        const f16* Kb = lds + (kt & 1)*8192;
        const f16* Vb = lds + 16384 + (kt & 1)*8192;
        f16* Ps = lds + 32768;

        u32 mw[2][2];
#pragma unroll
        for (int qt = 0; qt < 2; qt++) {
            int qrow = q0 + w*32 + qt*16 + lane15;
            const u32* bp = bits + (((size_t)(b*L_ + qrow)) << 6) + (k0 >> 5);
            mw[qt][0] = bp[0];
            mw[qt][1] = bp[1];
        }

        // ---- S^T = K * Q^T
        f32x4 st[2][4];
        __builtin_amdgcn_s_setprio(1);
#pragma unroll
        for (int kt2 = 0; kt2 < 4; kt2++) {
            f16x8 kf[4];
#pragma unroll
            for (int dc = 0; dc < 4; dc++)
                kf[dc] = *(const f16x8*)&Kb[(kt2*16 + lane15)*128
                                            + (((dc*4 + quad) ^ lane15) * 8)];
#pragma unroll
            for (int qt = 0; qt < 2; qt++) {
                f32x4 a = {0.f, 0.f, 0.f, 0.f};
#pragma unroll
                for (int dc = 0; dc < 4; dc++)
                    a = __builtin_amdgcn_mfma_f32_16x16x32_f16(kf[dc], qf[qt][dc], a, 0, 0, 0);
                st[qt][kt2] = a;
            }
        }
        __builtin_amdgcn_s_setprio(0);

        // ---- poly soft-cap + mask + fixed-max exp, P -> LDS
#pragma unroll
        for (int qt = 0; qt < 2; qt++) {
            const int prow = (w*32 + qt*16 + lane15) * 64;
            float ls = 0.f;
#pragma unroll
            for (int kt2 = 0; kt2 < 4; kt2++) {
                const u32 w_ = mw[qt][kt2 >> 1];
                f16x4 ph;
#pragma unroll
                for (int r = 0; r < 4; r++) {
                    float x = st[qt][kt2][r];
                    float y = x * x;
                    float p5 = fmaf(CAP_C2, y, CAP_C1);
                    float wv = fmaf(p5, y, CAP_C0);
                    float e = fmaf(x, wv, -FIXED_M2);
                    int kk = kt2*16 + quad*4 + r;
                    e = ((w_ >> (kk & 31)) & 1u) ? e : -150.f;
                    float pv = fexp2(e);
                    ls += pv;
                    ph[r] = (f16)pv;
                }
                const int c16s = (kt2*2 + (quad >> 1)) ^ (lane15 & 7);
                *(f16x4*)&Ps[prow + c16s*8 + (quad & 1)*4] = ph;
            }
            lsum[qt] += ls;
        }
        // no barrier: PV reads only this wave's own Ps rows (in-order DS)

        // ---- O += P * V
        f16x8 pf[2][2];
#pragma unroll
        for (int qt = 0; qt < 2; qt++)
#pragma unroll
            for (int c = 0; c < 2; c++)
                pf[qt][c] = *(const f16x8*)&Ps[(w*32 + qt*16 + lane15)*64
                                               + (((c*4 + quad) ^ (lane15 & 7)) * 8)];
        __builtin_amdgcn_s_setprio(1);
#pragma unroll
        for (int dt = 0; dt < 8; dt++) {
            f16x8 vf[2];
#pragma unroll
            for (int c = 0; c < 2; c++)
                vf[c] = *(const f16x8*)&Vb[(dt*16 + lane15)*64
                                           + (((c*4 + quad) ^ (lane15 & 7)) * 8)];
#pragma unroll
            for (int qt = 0; qt < 2; qt++)
#pragma unroll
                for (int c = 0; c < 2; c++)
                    oacc[qt][dt] = __builtin_amdgcn_mfma_f32_16x16x32_f16(pf[qt][c], vf[c], oacc[qt][dt], 0, 0, 0);
        }
        __builtin_amdgcn_s_setprio(0);
    }

    // ---- epilogue: l-reduce over quads, divide, store via LDS repack
#pragma unroll
    for (int qt = 0; qt < 2; qt++) {
        lsum[qt] += __shfl_xor(lsum[qt], 16);
        lsum[qt] += __shfl_xor(lsum[qt], 32);
    }
    __syncthreads();   // all LDS reads done; reuse lds[0..17408) as Ot [128][136]
    f16* Ot = lds;
#pragma unroll
    for (int qt = 0; qt < 2; qt++) {
#pragma unroll
        for (int r = 0; r < 4; r++) {
            float inv = frcp(__shfl(lsum[qt], quad*4 + r));
            const int row = w*32 + qt*16 + quad*4 + r;
#pragma unroll
            for (int dt = 0; dt < 8; dt++)
                Ot[row*136 + dt*16 + lane15] = (f16)(oacc[qt][dt][r] * inv);
        }
    }
    __syncthreads();
#pragma unroll
    for (int i = 0; i < 8; i++) {
        int f = t + i*256;
        int row = f >> 4, ch = f & 15;
        *(uint4*)&AOh[qkbase + (size_t)(q0 + row)*HID_ + ch*8] =
            *(const uint4*)&Ot[row*136 + ch*8];
    }
}

// ---------------------------------------------------------------------------
extern "C" void kernel_launch(void* const* d_in, const int* in_sizes, int n_in,
                              void* d_out, int out_size, void* d_ws, size_t ws_size,
                              hipStream_t stream)
{
    const float* hs  = (const float*)d_in[0];
    const float* Wq  = (const float*)d_in[1];
    const float* Wk  = (const float*)d_in[2];
    const float* Wv  = (const float*)d_in[3];
    const float* Wo  = (const float*)d_in[4];
    const float* qw  = (const float*)d_in[5];
    const float* kw  = (const float*)d_in[6];
    const float* kb  = (const float*)d_in[7];
    const float* vb  = (const float*)d_in[8];
    const int*   pos = (const int*)d_in[9];
    const int*   mask = (const int*)d_in[10];
    float* out = (float*)d_out;

    char* W = (char*)d_ws;
    f16* hs16 = (f16*)(W);                     // 16.8 MB; later AOh
    f16* w16o = (f16*)(W + 16777216);          // 8.4 MB
    f16* w16q = (f16*)(W + 25165824);          // 8.4 MB
    f16* w16k = (f16*)(W + 33554432);          // 8.4 MB
    f16* w16v = (f16*)(W + 41943040);          // 8.4 MB; later bits
    f16* Q16  = (f16*)(W + 50331648);          // 16.8 MB
    f16* K16  = (f16*)(W + 67108864);          // 16.8 MB
    f16* Vtg  = (f16*)(W + 83886080);          // 16.8 MB (V written transposed)
    u32*  bits = (u32*) (W + 41943040);
    f16* AOh = hs16;

    const int M = B_ * L_;          // 4096

    cvt5<<<12288, 256, 0, stream>>>(hs, Wq, Wk, Wv, Wo,
                                    hs16, w16q, w16k, w16v, w16o);

    gemm8p_qkv<<<dim3(HID_/256, M/256, 3), 512, 0, stream>>>(
        hs16, w16q, w16k, w16v, Q16, K16, Vtg, vb, M, HID_, HID_, FAN_IN);

    mask_pack<<<1024, 256, 0, stream>>>(mask, bits);

    norm_rope<<<M, 256, 0, stream>>>(Q16, K16, qw, kw, kb, pos);

    flash16<<<dim3(16, 32), 256, 0, stream>>>(Q16, K16, Vtg, bits, AOh);

    gemm3b_o<<<dim3(16, 16), 256, 0, stream>>>(
        AOh, w16o, out, HID_, FAN_IN);
}